// Round 13
// baseline (628.321 us; speedup 1.0000x reference)
//
#include <hip/hip_runtime.h>
#include <cstdint>
#include <cstddef>

constexpr int Hd  = 256;
constexpr int N_P = 100000;
constexpr int N_A = 20000;
constexpr int F_P = 512;
constexpr int D_A = 128;

typedef short bf16x8 __attribute__((ext_vector_type(8)));
typedef float f32x4  __attribute__((ext_vector_type(4)));

// fp32 -> bf16 round-to-nearest-even
__device__ __forceinline__ unsigned short f2b(float x) {
    unsigned u = __float_as_uint(x);
    u += 0x7fffu + ((u >> 16) & 1u);
    return (unsigned short)(u >> 16);
}
__device__ __forceinline__ float b2f(unsigned short h) {
    return __uint_as_float((unsigned)h << 16);
}

// split fp32 into bf16 hi + bf16 lo (truncation; combined error ~2^-16 rel)
__device__ __forceinline__ void bsplit(float x, unsigned short& hi, unsigned short& lo) {
    const unsigned u = __float_as_uint(x);
    hi = (unsigned short)(u >> 16);
    const float r = x - __uint_as_float(u & 0xffff0000u);
    lo = (unsigned short)(__float_as_uint(r) >> 16);
}

// ---------------------------------------------------------------------------
// prep: pack W tables into MFMA B-fragment layout + bias concats.
//  blocks [0,128):    (W1sa|W1rw) K=128, bf16 hi/lo (author L1, 3-product)
//  blocks [128,384):  (W2sa|W2rw) K=256, bf16 hi/lo (author L2, 3-product)
//  blocks [384,896):  (W2rc|W2sp) K_eff=512: hi/lo INTERLEAVED as K-slices
//  blocks [896,1408): (W1sp|W1rc) K=512, bf16 RNE single
//  blocks [1408,1440): bias concats bc1, bcA2, bcP2, bcP1
// ---------------------------------------------------------------------------
__global__ void prep_kernel(const float* __restrict__ W1sa, const float* __restrict__ W1rw,
                            const float* __restrict__ W2sa, const float* __restrict__ W2rw,
                            const float* __restrict__ W2rc, const float* __restrict__ W2sp,
                            const float* __restrict__ W1sp, const float* __restrict__ W1rc,
                            const float* __restrict__ b1sa, const float* __restrict__ b1rw,
                            const float* __restrict__ b2sa, const float* __restrict__ b2rw,
                            const float* __restrict__ b2rc, const float* __restrict__ b2sp,
                            const float* __restrict__ b1sp, const float* __restrict__ b1rc,
                            unsigned short* __restrict__ w1h,  unsigned short* __restrict__ w1l,
                            unsigned short* __restrict__ wA2h, unsigned short* __restrict__ wA2l,
                            unsigned short* __restrict__ wP2m,
                            unsigned short* __restrict__ wP1h,
                            float* __restrict__ bc1, float* __restrict__ bcA2,
                            float* __restrict__ bcP2, float* __restrict__ bcP1) {
    const int b = blockIdx.x;
    const int l = threadIdx.x;
    if (b < 384) {
        const float *Wa, *Wb; unsigned short *wh, *wl; int rel;
        if (b < 128) { Wa = W1sa; Wb = W1rw; wh = w1h;  wl = w1l;  rel = b; }
        else         { Wa = W2sa; Wb = W2rw; wh = wA2h; wl = wA2l; rel = b - 128; }
        const int ks  = rel >> 5;
        const int nfg = rel & 31;
        const float* W = (nfg < 16) ? Wa : Wb;
        const int col  = (nfg & 15) * 16 + (l & 15);
        const size_t base = ((size_t)rel * 64 + l) * 8;
        #pragma unroll
        for (int j = 0; j < 8; ++j) {
            const int k = ks * 32 + ((l >> 4) * 8) + j;
            unsigned short h, lw;
            bsplit(W[(size_t)k * Hd + col], h, lw);
            wh[base + j] = h;
            wl[base + j] = lw;
        }
    } else if (b < 896) {
        // (W2rc|W2sp) hi/lo interleaved: eff-ks even -> hi, odd -> lo
        const int rel = b - 384;                  // [0,512)
        const int ks  = rel >> 5;                 // eff k-slice [0,16)
        const int nfg = rel & 31;
        const int part = ks & 1;
        const int ksl  = ks >> 1;                 // real k-slice [0,8)
        const float* W = (nfg < 16) ? W2rc : W2sp;
        const int col  = (nfg & 15) * 16 + (l & 15);
        const size_t base = ((size_t)rel * 64 + l) * 8;
        #pragma unroll
        for (int j = 0; j < 8; ++j) {
            const int k = ksl * 32 + ((l >> 4) * 8) + j;
            unsigned short h, lw;
            bsplit(W[(size_t)k * Hd + col], h, lw);
            wP2m[base + j] = part ? lw : h;
        }
    } else if (b < 1408) {
        const int rel = b - 896;                  // [0,512)
        const int ks  = rel >> 5;
        const int nfg = rel & 31;
        const float* W = (nfg < 16) ? W1sp : W1rc;
        const int col  = (nfg & 15) * 16 + (l & 15);
        const size_t base = ((size_t)rel * 64 + l) * 8;
        #pragma unroll
        for (int j = 0; j < 8; ++j) {
            const int k = ks * 32 + ((l >> 4) * 8) + j;
            wP1h[base + j] = f2b(W[(size_t)k * Hd + col]);
        }
    } else {
        const int t     = (b - 1408) * 64 + l;    // 0..2047
        const int which = t >> 9;
        const int idx   = t & 511;
        const float* src; float* dst;
        if (which == 0)      { src = (idx < 256) ? b1sa : b1rw; dst = bc1;  }
        else if (which == 1) { src = (idx < 256) ? b2sa : b2rw; dst = bcA2; }
        else if (which == 2) { src = (idx < 256) ? b2rc : b2sp; dst = bcP2; }
        else                 { src = (idx < 256) ? b1sp : b1rc; dst = bcP1; }
        dst[idx] = src[idx & 255];
    }
}

// ---------------------------------------------------------------------------
// STREAM MFMA GEMM: 64 rows/block, 4 row-frags x 8 col-frags per wave.
// Software-pipelined K-loop (2 slices/iter, named A/B register double
// buffers, statically indexed): loads for slice ks+1 issue BEFORE the MFMA
// burst of slice ks -> the 32-MFMA burst (~160cy) covers the L2 latency.
// No barriers in the K-loop (A is read-only in LDS after one staging sync).
//  ASRC=0: fp32 A truncated to bf16 (EXACT for binary pf)
//  ASRC=1: bf16 A.  adup=2 re-reads A frags for the interleaved hi/lo table.
// Guarded for Mtot not a multiple of 64. nks must be even and >= 4.
// ---------------------------------------------------------------------------
template<int ASRC>
__global__ void __launch_bounds__(256, 2)
mfma_stream_kernel(const void* __restrict__ Av, const int KA, const int nks, const int adup,
                   const unsigned short* __restrict__ wtab,
                   const float* __restrict__ bcat,
                   void* __restrict__ Oa, void* __restrict__ Ob,
                   const int bfA, const int bfB, const int actA, const int actB,
                   const int Mtot) {
    extern __shared__ char smem[];
    const int  tid = threadIdx.x;
    const int  wid = tid >> 6;
    const int  l   = tid & 63;
    const long m0  = (long)blockIdx.x * 64;
    const int  rowStride = 2 * KA;

    // ---- stage A[64][KA] bf16 to LDS (swizzled), once ----
    if constexpr (ASRC == 0) {
        const float* A = (const float*)Av;
        const int kq4 = KA >> 2;
        for (int i = tid; i < 64 * kq4; i += 256) {
            const int row = i / kq4;
            const int kq  = i - row * kq4;
            const long gr = min(m0 + row, (long)Mtot - 1);
            const float4 v = *(const float4*)(A + gr * KA + kq * 4);
            const ushort4 h = make_ushort4(
                (unsigned short)(__float_as_uint(v.x) >> 16),
                (unsigned short)(__float_as_uint(v.y) >> 16),
                (unsigned short)(__float_as_uint(v.z) >> 16),
                (unsigned short)(__float_as_uint(v.w) >> 16));
            const int ofs = row * rowStride + ((kq * 8) ^ ((row & 7) << 4));
            *(ushort4*)(smem + ofs) = h;
        }
    } else {
        const unsigned short* A = (const unsigned short*)Av;
        const int kq8 = KA >> 3;
        for (int i = tid; i < 64 * kq8; i += 256) {
            const int row = i / kq8;
            const int kq  = i - row * kq8;
            const long gr = min(m0 + row, (long)Mtot - 1);
            const uint4 v = *(const uint4*)(A + gr * KA + kq * 8);
            const int ofs = row * rowStride + ((kq * 16) ^ ((row & 7) << 4));
            *(uint4*)(smem + ofs) = v;
        }
    }
    __syncthreads();

    // ---- accumulators (4 row-frags x 8 col-frags), bias init ----
    f32x4 acc[4][8];
    #pragma unroll
    for (int nf = 0; nf < 8; ++nf) {
        const float b = bcat[wid * 128 + nf * 16 + (l & 15)];
        #pragma unroll
        for (int mf = 0; mf < 4; ++mf) acc[mf][nf] = (f32x4){b, b, b, b};
    }

    const int kb = (l >> 4) * 16;
    const int sw = (l & 7) << 4;
    const int rr = l & 15;

    bf16x8 a0_[4], a1_[4], b0_[8], b1_[8];

#define LOADB(B_, KS) { \
    const size_t wb_ = (((size_t)(KS) * 32 + wid * 8) * 64 + l) * 8; \
    _Pragma("unroll") \
    for (int nf = 0; nf < 8; ++nf) B_[nf] = *(const bf16x8*)(wtab + wb_ + (size_t)nf * 512); }
#define LOADA(A_, KS) { \
    const int ka_ = (adup == 2) ? ((KS) >> 1) : (KS); \
    const int bk_ = (ka_ * 64 + kb) ^ sw; \
    _Pragma("unroll") \
    for (int mf = 0; mf < 4; ++mf) A_[mf] = *(const bf16x8*)(smem + (mf * 16 + rr) * rowStride + bk_); }
#define DOMFMA(A_, B_) { \
    _Pragma("unroll") \
    for (int nf = 0; nf < 8; ++nf) { \
        _Pragma("unroll") \
        for (int mf = 0; mf < 4; ++mf) \
            acc[mf][nf] = __builtin_amdgcn_mfma_f32_16x16x32_bf16(A_[mf], B_[nf], acc[mf][nf], 0, 0, 0); } }

    LOADB(b0_, 0)
    LOADA(a0_, 0)
    int ks = 0;
    for (; ks + 2 < nks; ks += 2) {
        LOADB(b1_, ks + 1)
        LOADA(a1_, ks + 1)
        DOMFMA(a0_, b0_)
        LOADB(b0_, ks + 2)
        LOADA(a0_, ks + 2)
        DOMFMA(a1_, b1_)
    }
    LOADB(b1_, nks - 1)
    LOADA(a1_, nks - 1)
    DOMFMA(a0_, b0_)
    DOMFMA(a1_, b1_)
#undef LOADB
#undef LOADA
#undef DOMFMA

    // ---- epilogue (guarded) ----
    #pragma unroll
    for (int mf = 0; mf < 4; ++mf) {
        #pragma unroll
        for (int nf = 0; nf < 8; ++nf) {
            const int colg = wid * 128 + nf * 16 + (l & 15);
            void* O;
            int col, act, isbf;
            if (colg < 256) { O = Oa; col = colg;       act = actA; isbf = bfA; }
            else            { O = Ob; col = colg - 256; act = actB; isbf = bfB; }
            const long row = m0 + mf * 16 + ((l >> 4) * 4);
            const f32x4 v = acc[mf][nf];
            #pragma unroll
            for (int r = 0; r < 4; ++r) {
                if (row + r < Mtot) {
                    float x = v[r];
                    if (act) x = x > 0.f ? x : expm1f(x);
                    if (isbf) ((unsigned short*)O)[(row + r) * Hd + col] = f2b(x);
                    else      ((float*)O)[(row + r) * Hd + col] = x;
                }
            }
        }
    }
}

// ---------------------------------------------------------------------------
// Dual-output MFMA GEMM (author GEMMs only): fp32 A, split-bf16 3-product.
// 32 rows/block. Proven R7 structure, unchanged.
// ---------------------------------------------------------------------------
__global__ void mfma_dual_kernel(const void* __restrict__ Av, const int K,
                                 const unsigned short* __restrict__ whi,
                                 const unsigned short* __restrict__ wlo,
                                 const float* __restrict__ bcat,
                                 void* __restrict__ Oa, void* __restrict__ Ob,
                                 const int actA, const int actB,
                                 const int bfA, const int bfB) {
    extern __shared__ char smem[];
    char* sh = smem;
    char* sl = smem + 32 * K * 2;
    const int  tid = threadIdx.x;
    const int  wid = tid >> 6;
    const int  l   = tid & 63;
    const long m0  = (long)blockIdx.x * 32;
    const int  rowStride = 2 * K;

    const int kq4 = K >> 2;
    const float* A = (const float*)Av;
    for (int i = tid; i < 32 * kq4; i += 256) {
        const int row = i / kq4;
        const int kq  = i - row * kq4;
        const float4 v = *(const float4*)(A + (m0 + row) * K + kq * 4);
        unsigned short h0, h1, h2, h3, l0, l1, l2, l3;
        bsplit(v.x, h0, l0); bsplit(v.y, h1, l1);
        bsplit(v.z, h2, l2); bsplit(v.w, h3, l3);
        const int ofs = row * rowStride + ((kq * 8) ^ ((row & 7) << 4));
        *(ushort4*)(sh + ofs) = make_ushort4(h0, h1, h2, h3);
        *(ushort4*)(sl + ofs) = make_ushort4(l0, l1, l2, l3);
    }
    __syncthreads();

    f32x4 acc[2][8];
    #pragma unroll
    for (int nf = 0; nf < 8; ++nf) {
        const float b = bcat[wid * 128 + nf * 16 + (l & 15)];
        acc[0][nf] = (f32x4){b, b, b, b};
        acc[1][nf] = (f32x4){b, b, b, b};
    }

    const int kb  = (l >> 4) * 16;
    const int r0  = l & 15;
    const int r1  = 16 + r0;
    const int sw  = (l & 7) << 4;
    const int ro0 = r0 * rowStride;
    const int ro1 = r1 * rowStride;
    for (int ks = 0; ks < (K >> 5); ++ks) {
        const int bk = (ks * 64 + kb) ^ sw;
        const bf16x8 ah0 = *(const bf16x8*)(sh + ro0 + bk);
        const bf16x8 ah1 = *(const bf16x8*)(sh + ro1 + bk);
        const bf16x8 al0 = *(const bf16x8*)(sl + ro0 + bk);
        const bf16x8 al1 = *(const bf16x8*)(sl + ro1 + bk);
        const size_t wbase = (((size_t)ks * 32 + wid * 8) * 64 + l) * 8;
        #pragma unroll
        for (int nf = 0; nf < 8; ++nf) {
            const bf16x8 bh = *(const bf16x8*)(whi + wbase + (size_t)nf * 512);
            const bf16x8 bl = *(const bf16x8*)(wlo + wbase + (size_t)nf * 512);
            acc[0][nf] = __builtin_amdgcn_mfma_f32_16x16x32_bf16(ah0, bh, acc[0][nf], 0, 0, 0);
            acc[1][nf] = __builtin_amdgcn_mfma_f32_16x16x32_bf16(ah1, bh, acc[1][nf], 0, 0, 0);
            acc[0][nf] = __builtin_amdgcn_mfma_f32_16x16x32_bf16(al0, bh, acc[0][nf], 0, 0, 0);
            acc[1][nf] = __builtin_amdgcn_mfma_f32_16x16x32_bf16(al1, bh, acc[1][nf], 0, 0, 0);
            acc[0][nf] = __builtin_amdgcn_mfma_f32_16x16x32_bf16(ah0, bl, acc[0][nf], 0, 0, 0);
            acc[1][nf] = __builtin_amdgcn_mfma_f32_16x16x32_bf16(ah1, bl, acc[1][nf], 0, 0, 0);
        }
    }

    #pragma unroll
    for (int mf = 0; mf < 2; ++mf) {
        #pragma unroll
        for (int nf = 0; nf < 8; ++nf) {
            const int colg = wid * 128 + nf * 16 + (l & 15);
            void* O;
            int col, act, isbf;
            if (colg < 256) { O = Oa; col = colg;       act = actA; isbf = bfA; }
            else            { O = Ob; col = colg - 256; act = actB; isbf = bfB; }
            const long row = m0 + mf * 16 + ((l >> 4) * 4);
            const f32x4 v = acc[mf][nf];
            #pragma unroll
            for (int r = 0; r < 4; ++r) {
                float x = v[r];
                if (act) x = x > 0.f ? x : expm1f(x);
                if (isbf) ((unsigned short*)O)[(row + r) * Hd + col] = f2b(x);
                else      ((float*)O)[(row + r) * Hd + col] = x;
            }
        }
    }
}

// ---------------------------------------------------------------------------
// Combined-relation CSR build. src' = writes ? wsrc : N_A + csrc.
// After fill, off[p] = END of segment p.
// ---------------------------------------------------------------------------
__global__ void hist_kernel(const int* __restrict__ wdst, const int EW,
                            const int* __restrict__ cdst, const int EC,
                            int* __restrict__ cnt) {
    for (int i = blockIdx.x * blockDim.x + threadIdx.x; i < EW + EC; i += gridDim.x * blockDim.x) {
        const int d = (i < EW) ? wdst[i] : cdst[i - EW];
        atomicAdd(&cnt[d], 1);
    }
}

__global__ void scan1_kernel(int* __restrict__ data, const int n, int* __restrict__ bsum) {
    __shared__ int s[256];
    const int t = threadIdx.x;
    const int base = blockIdx.x * 1024 + t * 4;
    int v0 = (base + 0 < n) ? data[base + 0] : 0;
    int v1 = (base + 1 < n) ? data[base + 1] : 0;
    int v2 = (base + 2 < n) ? data[base + 2] : 0;
    int v3 = (base + 3 < n) ? data[base + 3] : 0;
    const int tsum = v0 + v1 + v2 + v3;
    s[t] = tsum;
    __syncthreads();
    for (int off = 1; off < 256; off <<= 1) {
        int y = (t >= off) ? s[t - off] : 0;
        __syncthreads();
        if (t >= off) s[t] += y;
        __syncthreads();
    }
    const int e = s[t] - tsum;
    if (base + 0 < n) data[base + 0] = e;
    if (base + 1 < n) data[base + 1] = e + v0;
    if (base + 2 < n) data[base + 2] = e + v0 + v1;
    if (base + 3 < n) data[base + 3] = e + v0 + v1 + v2;
    if (t == 255) bsum[blockIdx.x] = s[255];
}

__global__ void scan2_kernel(int* __restrict__ bsum, const int nb) {
    __shared__ int s[256];
    const int t = threadIdx.x;
    const int v = (t < nb) ? bsum[t] : 0;
    s[t] = v;
    __syncthreads();
    for (int off = 1; off < 256; off <<= 1) {
        int y = (t >= off) ? s[t - off] : 0;
        __syncthreads();
        if (t >= off) s[t] += y;
        __syncthreads();
    }
    if (t < nb) bsum[t] = s[t] - v;
}

__global__ void scan3_kernel(int* __restrict__ data, const int n, const int* __restrict__ bsum) {
    const int i = blockIdx.x * blockDim.x + threadIdx.x;
    if (i < n) data[i] += bsum[i >> 10];
}

__global__ void fill_kernel(const int* __restrict__ wsrc, const int* __restrict__ wdst,
                            const float* __restrict__ ww, const int EW,
                            const int* __restrict__ csrc, const int* __restrict__ cdst,
                            const float* __restrict__ cw, const int EC,
                            int* __restrict__ cur, int2* __restrict__ edges) {
    for (int i = blockIdx.x * blockDim.x + threadIdx.x; i < EW + EC; i += gridDim.x * blockDim.x) {
        int d, sp; float w;
        if (i < EW) { d = wdst[i]; sp = wsrc[i]; w = ww[i]; }
        else        { const int j = i - EW; d = cdst[j]; sp = N_A + csrc[j]; w = cw[j]; }
        const int p = atomicAdd(&cur[d], 1);
        edges[p] = make_int2(sp, __float_as_int(w));
    }
}

// ---------------------------------------------------------------------------
// Pull aggregation (R7-proven version). Block = 4 dests (1 per wave). Block
// stages its 4 dests' contiguous edge window into LDS eq[1024]; chunk-4 A/B
// ping-pong per wave. Serial fallback for >1024-edge windows.
// IOBF: io bf16 (layer 1) or fp32 (layer 2).
// ---------------------------------------------------------------------------
struct AgChunk { ushort4 g0, g1, g2, g3; float w0, w1, w2, w3; };

__device__ __forceinline__ void ag_issue(const int2* __restrict__ eq, const int base, const int n,
                                         const unsigned short* __restrict__ msg,
                                         const int lane, AgChunk& C) {
#define AG_ONE(J, GG, WW) { \
    const int idx = base + (J); \
    const int2 ee = eq[min(idx, n - 1)]; \
    WW = (idx < n) ? __int_as_float(ee.y) : 0.f; \
    GG = ((const ushort4*)(msg + (size_t)ee.x * Hd))[lane]; }
    AG_ONE(0, C.g0, C.w0)
    AG_ONE(1, C.g1, C.w1)
    AG_ONE(2, C.g2, C.w2)
    AG_ONE(3, C.g3, C.w3)
#undef AG_ONE
}

__device__ __forceinline__ void ag_acc(const AgChunk& C, float4& acc) {
#define AG_A(GG, WW) { \
    acc.x = fmaf(WW, b2f(GG.x), acc.x); acc.y = fmaf(WW, b2f(GG.y), acc.y); \
    acc.z = fmaf(WW, b2f(GG.z), acc.z); acc.w = fmaf(WW, b2f(GG.w), acc.w); }
    AG_A(C.g0, C.w0) AG_A(C.g1, C.w1) AG_A(C.g2, C.w2) AG_A(C.g3, C.w3)
#undef AG_A
}

template<int IOBF>
__global__ void aggregate_kernel(void* __restrict__ iov,
                                 const unsigned short* __restrict__ msgAll,
                                 const int* __restrict__ off,
                                 const int2* __restrict__ edges,
                                 const int do_elu) {
    __shared__ int2 eq[1024];
    const int wid  = threadIdx.x >> 6;
    const int lane = threadIdx.x & 63;
    const int p0   = blockIdx.x * 4;
    const int sAll = (p0 == 0) ? 0 : off[p0 - 1];
    const int tot  = off[p0 + 3] - sAll;
    const bool fits = (tot <= 1024);
    if (fits)
        for (int i = threadIdx.x; i < tot; i += 256) eq[i] = edges[sAll + i];
    __syncthreads();

    const int p = p0 + wid;
    const int s = (p == 0) ? 0 : off[p - 1];
    const int e = off[p];
    const int n = e - s;

    float4 acc;
    if constexpr (IOBF) {
        const ushort4 t = ((const ushort4*)((const unsigned short*)iov + (size_t)p * Hd))[lane];
        acc = make_float4(b2f(t.x), b2f(t.y), b2f(t.z), b2f(t.w));
    } else {
        acc = ((const float4*)((const float*)iov + (size_t)p * Hd))[lane];
    }

    if (n > 0) {
        if (fits) {
            const int2* eqw = eq + (s - sAll);
            int nc = (n + 3) >> 2;
            nc += (nc & 1);                       // even, >= 2
            AgChunk CA, CB;
            ag_issue(eqw, 0, n, msgAll, lane, CA);
            int c = 1;
            for (; c + 1 < nc; c += 2) {
                ag_issue(eqw, 4 * c, n, msgAll, lane, CB);
                ag_acc(CA, acc);
                ag_issue(eqw, 4 * (c + 1), n, msgAll, lane, CA);
                ag_acc(CB, acc);
            }
            ag_issue(eqw, 4 * (nc - 1), n, msgAll, lane, CB);
            ag_acc(CA, acc);
            ag_acc(CB, acc);
        } else {
            for (int i = s; i < e; ++i) {
                const int2 ee = edges[i];
                const ushort4 g = ((const ushort4*)(msgAll + (size_t)ee.x * Hd))[lane];
                const float w = __int_as_float(ee.y);
                acc.x = fmaf(w, b2f(g.x), acc.x); acc.y = fmaf(w, b2f(g.y), acc.y);
                acc.z = fmaf(w, b2f(g.z), acc.z); acc.w = fmaf(w, b2f(g.w), acc.w);
            }
        }
    }
    if (do_elu) {
        acc.x = acc.x > 0.f ? acc.x : expm1f(acc.x);
        acc.y = acc.y > 0.f ? acc.y : expm1f(acc.y);
        acc.z = acc.z > 0.f ? acc.z : expm1f(acc.z);
        acc.w = acc.w > 0.f ? acc.w : expm1f(acc.w);
    }
    if constexpr (IOBF) {
        ((ushort4*)((unsigned short*)iov + (size_t)p * Hd))[lane] =
            make_ushort4(f2b(acc.x), f2b(acc.y), f2b(acc.z), f2b(acc.w));
    } else {
        ((float4*)((float*)iov + (size_t)p * Hd))[lane] = acc;
    }
}

extern "C" void kernel_launch(void* const* d_in, const int* in_sizes, int n_in,
                              void* d_out, int out_size, void* d_ws, size_t ws_size,
                              hipStream_t stream) {
    const float* pf    = (const float*)d_in[0];
    const float* ae    = (const float*)d_in[1];
    const int*   wsrc  = (const int*)d_in[2];
    const int*   wdst  = (const int*)d_in[3];
    const float* ww    = (const float*)d_in[4];
    const int*   csrc  = (const int*)d_in[5];
    const int*   cdst  = (const int*)d_in[6];
    const float* cw    = (const float*)d_in[7];
    const float* W1sp  = (const float*)d_in[8];
    const float* b1sp  = (const float*)d_in[9];
    const float* W1sa  = (const float*)d_in[10];
    const float* b1sa  = (const float*)d_in[11];
    const float* W1rw  = (const float*)d_in[12];
    const float* b1rw  = (const float*)d_in[13];
    const float* W1rc  = (const float*)d_in[14];
    const float* b1rc  = (const float*)d_in[15];
    const float* W2sp  = (const float*)d_in[16];
    const float* b2sp  = (const float*)d_in[17];
    const float* W2sa  = (const float*)d_in[18];
    const float* b2sa  = (const float*)d_in[19];
    const float* W2rw  = (const float*)d_in[20];
    const float* b2rw  = (const float*)d_in[21];
    const float* W2rc  = (const float*)d_in[22];
    const float* b2rc  = (const float*)d_in[23];

    const int E_W = in_sizes[2];
    const int E_C = in_sizes[5];

    float* outP = (float*)d_out;                        // [N_P, 256] fp32
    float* outA = outP + (size_t)N_P * Hd;              // [N_A, 256] fp32

    // Workspace layout:
    // xa1 f32[N_A*256] | xp1b u16[N_P*256] | msgAll u16[(N_A+N_P)*256] |
    // off[N_P] | edges int2[E] | bsum[256] | bc1 bcA2 bcP2 bcP1 f32[512 each] |
    // w1h w1l | wA2h wA2l | wP2m | wP1h
    float*          xa1    = (float*)d_ws;
    unsigned short* xp1b   = (unsigned short*)(xa1 + (size_t)N_A * Hd);
    unsigned short* msgAll = xp1b + (size_t)N_P * Hd;
    unsigned short* msgP   = msgAll + (size_t)N_A * Hd;
    int*            off    = (int*)(msgAll + (size_t)(N_A + N_P) * Hd);
    int2*           edges  = (int2*)(off + N_P);
    int*            bsum   = (int*)(edges + (E_W + E_C));
    float*          bc1    = (float*)(bsum + 256);
    float*          bcA2   = bc1 + 512;
    float*          bcP2   = bcA2 + 512;
    float*          bcP1   = bcP2 + 512;
    unsigned short* w1h    = (unsigned short*)(bcP1 + 512);
    unsigned short* w1l    = w1h  + (size_t)128 * 512;
    unsigned short* wA2h   = w1l  + (size_t)128 * 512;
    unsigned short* wA2l   = wA2h + (size_t)256 * 512;
    unsigned short* wP2m   = wA2l + (size_t)256 * 512;   // 512*512 shorts
    unsigned short* wP1h   = wP2m + (size_t)512 * 512;

    const dim3 blk(256);
    const int  nb = (N_P + 1023) / 1024;      // 98
    const int  gP = (N_P + 63) / 64;          // 1563 (last block partial)

    // ---------------- prep ----------------
    prep_kernel<<<1440, 64, 0, stream>>>(W1sa, W1rw, W2sa, W2rw, W2rc, W2sp, W1sp, W1rc,
                                         b1sa, b1rw, b2sa, b2rw, b2rc, b2sp, b1sp, b1rc,
                                         w1h, w1l, wA2h, wA2l, wP2m, wP1h,
                                         bc1, bcA2, bcP2, bcP1);

    // ---------------- combined CSR ----------------
    hipMemsetAsync(off, 0, (size_t)N_P * sizeof(int), stream);
    hist_kernel<<<1024, blk, 0, stream>>>(wdst, E_W, cdst, E_C, off);
    scan1_kernel<<<nb, blk, 0, stream>>>(off, N_P, bsum);
    scan2_kernel<<<1,  blk, 0, stream>>>(bsum, nb);
    scan3_kernel<<<(N_P + 255) / 256, blk, 0, stream>>>(off, N_P, bsum);
    fill_kernel<<<1024, blk, 0, stream>>>(wsrc, wdst, ww, E_W, csrc, cdst, cw, E_C,
                                          off, edges);

    // ---------------- Layer 1 ----------------
    // paper self + cites msg: streamed mono GEMM over binary pf (K=512)
    mfma_stream_kernel<0><<<gP, blk, 64 * 512 * 2, stream>>>(pf, 512, 16, 1, wP1h, bcP1,
                                                             xp1b, msgP, 1, 1, 0, 0, N_P);
    // author self (ELU, fp32 xa1) + writes msg (bf16 into msgAll)
    mfma_dual_kernel<<<N_A / 32, blk, 32 * 128 * 4, stream>>>(ae, 128, w1h, w1l, bc1,
                                                              xa1, msgAll, 1, 0, 0, 1);
    aggregate_kernel<1><<<N_P / 4, blk, 0, stream>>>(xp1b, msgAll, off, edges, 1);

    // ---------------- Layer 2 ----------------
    mfma_dual_kernel<<<N_A / 32, blk, 32 * 256 * 4, stream>>>(xa1, 256, wA2h, wA2l, bcA2,
                                                              outA, msgAll, 0, 0, 0, 1);
    // paper: A = xp1b (bf16), interleaved hi/lo B (K_eff=512, exact 2-product)
    mfma_stream_kernel<1><<<gP, blk, 64 * 256 * 2, stream>>>(xp1b, 256, 16, 2, wP2m, bcP2,
                                                             msgP, outP, 1, 0, 0, 0, N_P);
    aggregate_kernel<0><<<N_P / 4, blk, 0, stream>>>(outP, msgAll, off, edges, 0);
}

// Round 14
// 627.393 us; speedup vs baseline: 1.0015x; 1.0015x over previous
//
#include <hip/hip_runtime.h>
#include <cstdint>
#include <cstddef>

constexpr int Hd  = 256;
constexpr int N_P = 100000;
constexpr int N_A = 20000;
constexpr int F_P = 512;
constexpr int D_A = 128;

typedef short bf16x8 __attribute__((ext_vector_type(8)));
typedef float f32x4  __attribute__((ext_vector_type(4)));

// fp32 -> bf16 round-to-nearest-even
__device__ __forceinline__ unsigned short f2b(float x) {
    unsigned u = __float_as_uint(x);
    u += 0x7fffu + ((u >> 16) & 1u);
    return (unsigned short)(u >> 16);
}
__device__ __forceinline__ float b2f(unsigned short h) {
    return __uint_as_float((unsigned)h << 16);
}

// split fp32 into bf16 hi + bf16 lo (truncation; combined error ~2^-16 rel)
__device__ __forceinline__ void bsplit(float x, unsigned short& hi, unsigned short& lo) {
    const unsigned u = __float_as_uint(x);
    hi = (unsigned short)(u >> 16);
    const float r = x - __uint_as_float(u & 0xffff0000u);
    lo = (unsigned short)(__float_as_uint(r) >> 16);
}

// ---------------------------------------------------------------------------
// prep: pack W tables into MFMA B-fragment layout + bias concats.
//  blocks [0,128):    (W1sa|W1rw) K=128, bf16 hi/lo (author L1, 3-product)
//  blocks [128,384):  (W2sa|W2rw) K=256, bf16 hi/lo (author L2, 3-product)
//  blocks [384,896):  (W2rc|W2sp) K_eff=512: hi/lo INTERLEAVED as K-slices
//  blocks [896,1408): (W1sp|W1rc) K=512, bf16 RNE single
//  blocks [1408,1440): bias concats bc1, bcA2, bcP2, bcP1
// ---------------------------------------------------------------------------
__global__ void prep_kernel(const float* __restrict__ W1sa, const float* __restrict__ W1rw,
                            const float* __restrict__ W2sa, const float* __restrict__ W2rw,
                            const float* __restrict__ W2rc, const float* __restrict__ W2sp,
                            const float* __restrict__ W1sp, const float* __restrict__ W1rc,
                            const float* __restrict__ b1sa, const float* __restrict__ b1rw,
                            const float* __restrict__ b2sa, const float* __restrict__ b2rw,
                            const float* __restrict__ b2rc, const float* __restrict__ b2sp,
                            const float* __restrict__ b1sp, const float* __restrict__ b1rc,
                            unsigned short* __restrict__ w1h,  unsigned short* __restrict__ w1l,
                            unsigned short* __restrict__ wA2h, unsigned short* __restrict__ wA2l,
                            unsigned short* __restrict__ wP2m,
                            unsigned short* __restrict__ wP1h,
                            float* __restrict__ bc1, float* __restrict__ bcA2,
                            float* __restrict__ bcP2, float* __restrict__ bcP1) {
    const int b = blockIdx.x;
    const int l = threadIdx.x;
    if (b < 384) {
        const float *Wa, *Wb; unsigned short *wh, *wl; int rel;
        if (b < 128) { Wa = W1sa; Wb = W1rw; wh = w1h;  wl = w1l;  rel = b; }
        else         { Wa = W2sa; Wb = W2rw; wh = wA2h; wl = wA2l; rel = b - 128; }
        const int ks  = rel >> 5;
        const int nfg = rel & 31;
        const float* W = (nfg < 16) ? Wa : Wb;
        const int col  = (nfg & 15) * 16 + (l & 15);
        const size_t base = ((size_t)rel * 64 + l) * 8;
        #pragma unroll
        for (int j = 0; j < 8; ++j) {
            const int k = ks * 32 + ((l >> 4) * 8) + j;
            unsigned short h, lw;
            bsplit(W[(size_t)k * Hd + col], h, lw);
            wh[base + j] = h;
            wl[base + j] = lw;
        }
    } else if (b < 896) {
        // (W2rc|W2sp) hi/lo interleaved: eff-ks even -> hi, odd -> lo
        const int rel = b - 384;                  // [0,512)
        const int ks  = rel >> 5;                 // eff k-slice [0,16)
        const int nfg = rel & 31;
        const int part = ks & 1;
        const int ksl  = ks >> 1;                 // real k-slice [0,8)
        const float* W = (nfg < 16) ? W2rc : W2sp;
        const int col  = (nfg & 15) * 16 + (l & 15);
        const size_t base = ((size_t)rel * 64 + l) * 8;
        #pragma unroll
        for (int j = 0; j < 8; ++j) {
            const int k = ksl * 32 + ((l >> 4) * 8) + j;
            unsigned short h, lw;
            bsplit(W[(size_t)k * Hd + col], h, lw);
            wP2m[base + j] = part ? lw : h;
        }
    } else if (b < 1408) {
        const int rel = b - 896;                  // [0,512)
        const int ks  = rel >> 5;
        const int nfg = rel & 31;
        const float* W = (nfg < 16) ? W1sp : W1rc;
        const int col  = (nfg & 15) * 16 + (l & 15);
        const size_t base = ((size_t)rel * 64 + l) * 8;
        #pragma unroll
        for (int j = 0; j < 8; ++j) {
            const int k = ks * 32 + ((l >> 4) * 8) + j;
            wP1h[base + j] = f2b(W[(size_t)k * Hd + col]);
        }
    } else {
        const int t     = (b - 1408) * 64 + l;    // 0..2047
        const int which = t >> 9;
        const int idx   = t & 511;
        const float* src; float* dst;
        if (which == 0)      { src = (idx < 256) ? b1sa : b1rw; dst = bc1;  }
        else if (which == 1) { src = (idx < 256) ? b2sa : b2rw; dst = bcA2; }
        else if (which == 2) { src = (idx < 256) ? b2rc : b2sp; dst = bcP2; }
        else                 { src = (idx < 256) ? b1sp : b1rc; dst = bcP1; }
        dst[idx] = src[idx & 255];
    }
}

// ---------------------------------------------------------------------------
// STREAM MFMA GEMM: 64 rows/block, 4 row-frags x 8 col-frags per wave.
// Software-pipelined K-loop (2 slices/iter, named A/B register double
// buffers, statically indexed): loads for slice ks+1 issue BEFORE the MFMA
// burst of slice ks -> the 32-MFMA burst (~160cy) covers the L2 latency.
// No barriers in the K-loop (A is read-only in LDS after one staging sync).
//  ASRC=0: fp32 A truncated to bf16 (EXACT for binary pf)
//  ASRC=1: bf16 A.  adup=2 re-reads A frags for the interleaved hi/lo table.
// Guarded for Mtot not a multiple of 64. nks must be even and >= 4.
// ---------------------------------------------------------------------------
template<int ASRC>
__global__ void __launch_bounds__(256, 2)
mfma_stream_kernel(const void* __restrict__ Av, const int KA, const int nks, const int adup,
                   const unsigned short* __restrict__ wtab,
                   const float* __restrict__ bcat,
                   void* __restrict__ Oa, void* __restrict__ Ob,
                   const int bfA, const int bfB, const int actA, const int actB,
                   const int Mtot) {
    extern __shared__ char smem[];
    const int  tid = threadIdx.x;
    const int  wid = tid >> 6;
    const int  l   = tid & 63;
    const long m0  = (long)blockIdx.x * 64;
    const int  rowStride = 2 * KA;

    // ---- stage A[64][KA] bf16 to LDS (swizzled), once ----
    if constexpr (ASRC == 0) {
        const float* A = (const float*)Av;
        const int kq4 = KA >> 2;
        for (int i = tid; i < 64 * kq4; i += 256) {
            const int row = i / kq4;
            const int kq  = i - row * kq4;
            const long gr = min(m0 + row, (long)Mtot - 1);
            const float4 v = *(const float4*)(A + gr * KA + kq * 4);
            const ushort4 h = make_ushort4(
                (unsigned short)(__float_as_uint(v.x) >> 16),
                (unsigned short)(__float_as_uint(v.y) >> 16),
                (unsigned short)(__float_as_uint(v.z) >> 16),
                (unsigned short)(__float_as_uint(v.w) >> 16));
            const int ofs = row * rowStride + ((kq * 8) ^ ((row & 7) << 4));
            *(ushort4*)(smem + ofs) = h;
        }
    } else {
        const unsigned short* A = (const unsigned short*)Av;
        const int kq8 = KA >> 3;
        for (int i = tid; i < 64 * kq8; i += 256) {
            const int row = i / kq8;
            const int kq  = i - row * kq8;
            const long gr = min(m0 + row, (long)Mtot - 1);
            const uint4 v = *(const uint4*)(A + gr * KA + kq * 8);
            const int ofs = row * rowStride + ((kq * 16) ^ ((row & 7) << 4));
            *(uint4*)(smem + ofs) = v;
        }
    }
    __syncthreads();

    // ---- accumulators (4 row-frags x 8 col-frags), bias init ----
    f32x4 acc[4][8];
    #pragma unroll
    for (int nf = 0; nf < 8; ++nf) {
        const float b = bcat[wid * 128 + nf * 16 + (l & 15)];
        #pragma unroll
        for (int mf = 0; mf < 4; ++mf) acc[mf][nf] = (f32x4){b, b, b, b};
    }

    const int kb = (l >> 4) * 16;
    const int sw = (l & 7) << 4;
    const int rr = l & 15;

    bf16x8 a0_[4], a1_[4], b0_[8], b1_[8];

#define LOADB(B_, KS) { \
    const size_t wb_ = (((size_t)(KS) * 32 + wid * 8) * 64 + l) * 8; \
    _Pragma("unroll") \
    for (int nf = 0; nf < 8; ++nf) B_[nf] = *(const bf16x8*)(wtab + wb_ + (size_t)nf * 512); }
#define LOADA(A_, KS) { \
    const int ka_ = (adup == 2) ? ((KS) >> 1) : (KS); \
    const int bk_ = (ka_ * 64 + kb) ^ sw; \
    _Pragma("unroll") \
    for (int mf = 0; mf < 4; ++mf) A_[mf] = *(const bf16x8*)(smem + (mf * 16 + rr) * rowStride + bk_); }
#define DOMFMA(A_, B_) { \
    _Pragma("unroll") \
    for (int nf = 0; nf < 8; ++nf) { \
        _Pragma("unroll") \
        for (int mf = 0; mf < 4; ++mf) \
            acc[mf][nf] = __builtin_amdgcn_mfma_f32_16x16x32_bf16(A_[mf], B_[nf], acc[mf][nf], 0, 0, 0); } }

    LOADB(b0_, 0)
    LOADA(a0_, 0)
    int ks = 0;
    for (; ks + 2 < nks; ks += 2) {
        LOADB(b1_, ks + 1)
        LOADA(a1_, ks + 1)
        DOMFMA(a0_, b0_)
        LOADB(b0_, ks + 2)
        LOADA(a0_, ks + 2)
        DOMFMA(a1_, b1_)
    }
    LOADB(b1_, nks - 1)
    LOADA(a1_, nks - 1)
    DOMFMA(a0_, b0_)
    DOMFMA(a1_, b1_)
#undef LOADB
#undef LOADA
#undef DOMFMA

    // ---- epilogue (guarded) ----
    #pragma unroll
    for (int mf = 0; mf < 4; ++mf) {
        #pragma unroll
        for (int nf = 0; nf < 8; ++nf) {
            const int colg = wid * 128 + nf * 16 + (l & 15);
            void* O;
            int col, act, isbf;
            if (colg < 256) { O = Oa; col = colg;       act = actA; isbf = bfA; }
            else            { O = Ob; col = colg - 256; act = actB; isbf = bfB; }
            const long row = m0 + mf * 16 + ((l >> 4) * 4);
            const f32x4 v = acc[mf][nf];
            #pragma unroll
            for (int r = 0; r < 4; ++r) {
                if (row + r < Mtot) {
                    float x = v[r];
                    if (act) x = x > 0.f ? x : expm1f(x);
                    if (isbf) ((unsigned short*)O)[(row + r) * Hd + col] = f2b(x);
                    else      ((float*)O)[(row + r) * Hd + col] = x;
                }
            }
        }
    }
}

// ---------------------------------------------------------------------------
// Dual-output MFMA GEMM (author GEMMs only): fp32 A, split-bf16 3-product.
// 32 rows/block. Proven R7 structure, unchanged.
// ---------------------------------------------------------------------------
__global__ void mfma_dual_kernel(const void* __restrict__ Av, const int K,
                                 const unsigned short* __restrict__ whi,
                                 const unsigned short* __restrict__ wlo,
                                 const float* __restrict__ bcat,
                                 void* __restrict__ Oa, void* __restrict__ Ob,
                                 const int actA, const int actB,
                                 const int bfA, const int bfB) {
    extern __shared__ char smem[];
    char* sh = smem;
    char* sl = smem + 32 * K * 2;
    const int  tid = threadIdx.x;
    const int  wid = tid >> 6;
    const int  l   = tid & 63;
    const long m0  = (long)blockIdx.x * 32;
    const int  rowStride = 2 * K;

    const int kq4 = K >> 2;
    const float* A = (const float*)Av;
    for (int i = tid; i < 32 * kq4; i += 256) {
        const int row = i / kq4;
        const int kq  = i - row * kq4;
        const float4 v = *(const float4*)(A + (m0 + row) * K + kq * 4);
        unsigned short h0, h1, h2, h3, l0, l1, l2, l3;
        bsplit(v.x, h0, l0); bsplit(v.y, h1, l1);
        bsplit(v.z, h2, l2); bsplit(v.w, h3, l3);
        const int ofs = row * rowStride + ((kq * 8) ^ ((row & 7) << 4));
        *(ushort4*)(sh + ofs) = make_ushort4(h0, h1, h2, h3);
        *(ushort4*)(sl + ofs) = make_ushort4(l0, l1, l2, l3);
    }
    __syncthreads();

    f32x4 acc[2][8];
    #pragma unroll
    for (int nf = 0; nf < 8; ++nf) {
        const float b = bcat[wid * 128 + nf * 16 + (l & 15)];
        acc[0][nf] = (f32x4){b, b, b, b};
        acc[1][nf] = (f32x4){b, b, b, b};
    }

    const int kb  = (l >> 4) * 16;
    const int r0  = l & 15;
    const int r1  = 16 + r0;
    const int sw  = (l & 7) << 4;
    const int ro0 = r0 * rowStride;
    const int ro1 = r1 * rowStride;
    for (int ks = 0; ks < (K >> 5); ++ks) {
        const int bk = (ks * 64 + kb) ^ sw;
        const bf16x8 ah0 = *(const bf16x8*)(sh + ro0 + bk);
        const bf16x8 ah1 = *(const bf16x8*)(sh + ro1 + bk);
        const bf16x8 al0 = *(const bf16x8*)(sl + ro0 + bk);
        const bf16x8 al1 = *(const bf16x8*)(sl + ro1 + bk);
        const size_t wbase = (((size_t)ks * 32 + wid * 8) * 64 + l) * 8;
        #pragma unroll
        for (int nf = 0; nf < 8; ++nf) {
            const bf16x8 bh = *(const bf16x8*)(whi + wbase + (size_t)nf * 512);
            const bf16x8 bl = *(const bf16x8*)(wlo + wbase + (size_t)nf * 512);
            acc[0][nf] = __builtin_amdgcn_mfma_f32_16x16x32_bf16(ah0, bh, acc[0][nf], 0, 0, 0);
            acc[1][nf] = __builtin_amdgcn_mfma_f32_16x16x32_bf16(ah1, bh, acc[1][nf], 0, 0, 0);
            acc[0][nf] = __builtin_amdgcn_mfma_f32_16x16x32_bf16(al0, bh, acc[0][nf], 0, 0, 0);
            acc[1][nf] = __builtin_amdgcn_mfma_f32_16x16x32_bf16(al1, bh, acc[1][nf], 0, 0, 0);
            acc[0][nf] = __builtin_amdgcn_mfma_f32_16x16x32_bf16(ah0, bl, acc[0][nf], 0, 0, 0);
            acc[1][nf] = __builtin_amdgcn_mfma_f32_16x16x32_bf16(ah1, bl, acc[1][nf], 0, 0, 0);
        }
    }

    #pragma unroll
    for (int mf = 0; mf < 2; ++mf) {
        #pragma unroll
        for (int nf = 0; nf < 8; ++nf) {
            const int colg = wid * 128 + nf * 16 + (l & 15);
            void* O;
            int col, act, isbf;
            if (colg < 256) { O = Oa; col = colg;       act = actA; isbf = bfA; }
            else            { O = Ob; col = colg - 256; act = actB; isbf = bfB; }
            const long row = m0 + mf * 16 + ((l >> 4) * 4);
            const f32x4 v = acc[mf][nf];
            #pragma unroll
            for (int r = 0; r < 4; ++r) {
                float x = v[r];
                if (act) x = x > 0.f ? x : expm1f(x);
                if (isbf) ((unsigned short*)O)[(row + r) * Hd + col] = f2b(x);
                else      ((float*)O)[(row + r) * Hd + col] = x;
            }
        }
    }
}

// ---------------------------------------------------------------------------
// Combined-relation CSR build. src' = writes ? wsrc : N_A + csrc.
// After fill, off[p] = END of segment p.
// ---------------------------------------------------------------------------
__global__ void hist_kernel(const int* __restrict__ wdst, const int EW,
                            const int* __restrict__ cdst, const int EC,
                            int* __restrict__ cnt) {
    for (int i = blockIdx.x * blockDim.x + threadIdx.x; i < EW + EC; i += gridDim.x * blockDim.x) {
        const int d = (i < EW) ? wdst[i] : cdst[i - EW];
        atomicAdd(&cnt[d], 1);
    }
}

__global__ void scan1_kernel(int* __restrict__ data, const int n, int* __restrict__ bsum) {
    __shared__ int s[256];
    const int t = threadIdx.x;
    const int base = blockIdx.x * 1024 + t * 4;
    int v0 = (base + 0 < n) ? data[base + 0] : 0;
    int v1 = (base + 1 < n) ? data[base + 1] : 0;
    int v2 = (base + 2 < n) ? data[base + 2] : 0;
    int v3 = (base + 3 < n) ? data[base + 3] : 0;
    const int tsum = v0 + v1 + v2 + v3;
    s[t] = tsum;
    __syncthreads();
    for (int off = 1; off < 256; off <<= 1) {
        int y = (t >= off) ? s[t - off] : 0;
        __syncthreads();
        if (t >= off) s[t] += y;
        __syncthreads();
    }
    const int e = s[t] - tsum;
    if (base + 0 < n) data[base + 0] = e;
    if (base + 1 < n) data[base + 1] = e + v0;
    if (base + 2 < n) data[base + 2] = e + v0 + v1;
    if (base + 3 < n) data[base + 3] = e + v0 + v1 + v2;
    if (t == 255) bsum[blockIdx.x] = s[255];
}

__global__ void scan2_kernel(int* __restrict__ bsum, const int nb) {
    __shared__ int s[256];
    const int t = threadIdx.x;
    const int v = (t < nb) ? bsum[t] : 0;
    s[t] = v;
    __syncthreads();
    for (int off = 1; off < 256; off <<= 1) {
        int y = (t >= off) ? s[t - off] : 0;
        __syncthreads();
        if (t >= off) s[t] += y;
        __syncthreads();
    }
    if (t < nb) bsum[t] = s[t] - v;
}

__global__ void scan3_kernel(int* __restrict__ data, const int n, const int* __restrict__ bsum) {
    const int i = blockIdx.x * blockDim.x + threadIdx.x;
    if (i < n) data[i] += bsum[i >> 10];
}

__global__ void fill_kernel(const int* __restrict__ wsrc, const int* __restrict__ wdst,
                            const float* __restrict__ ww, const int EW,
                            const int* __restrict__ csrc, const int* __restrict__ cdst,
                            const float* __restrict__ cw, const int EC,
                            int* __restrict__ cur, int2* __restrict__ edges) {
    for (int i = blockIdx.x * blockDim.x + threadIdx.x; i < EW + EC; i += gridDim.x * blockDim.x) {
        int d, sp; float w;
        if (i < EW) { d = wdst[i]; sp = wsrc[i]; w = ww[i]; }
        else        { const int j = i - EW; d = cdst[j]; sp = N_A + csrc[j]; w = cw[j]; }
        const int p = atomicAdd(&cur[d], 1);
        edges[p] = make_int2(sp, __float_as_int(w));
    }
}

// ---------------------------------------------------------------------------
// Pull aggregation (R7-proven version). Block = 4 dests (1 per wave). Block
// stages its 4 dests' contiguous edge window into LDS eq[1024]; chunk-4 A/B
// ping-pong per wave. Serial fallback for >1024-edge windows.
// IOBF: io bf16 (layer 1) or fp32 (layer 2).
// ---------------------------------------------------------------------------
struct AgChunk { ushort4 g0, g1, g2, g3; float w0, w1, w2, w3; };

__device__ __forceinline__ void ag_issue(const int2* __restrict__ eq, const int base, const int n,
                                         const unsigned short* __restrict__ msg,
                                         const int lane, AgChunk& C) {
#define AG_ONE(J, GG, WW) { \
    const int idx = base + (J); \
    const int2 ee = eq[min(idx, n - 1)]; \
    WW = (idx < n) ? __int_as_float(ee.y) : 0.f; \
    GG = ((const ushort4*)(msg + (size_t)ee.x * Hd))[lane]; }
    AG_ONE(0, C.g0, C.w0)
    AG_ONE(1, C.g1, C.w1)
    AG_ONE(2, C.g2, C.w2)
    AG_ONE(3, C.g3, C.w3)
#undef AG_ONE
}

__device__ __forceinline__ void ag_acc(const AgChunk& C, float4& acc) {
#define AG_A(GG, WW) { \
    acc.x = fmaf(WW, b2f(GG.x), acc.x); acc.y = fmaf(WW, b2f(GG.y), acc.y); \
    acc.z = fmaf(WW, b2f(GG.z), acc.z); acc.w = fmaf(WW, b2f(GG.w), acc.w); }
    AG_A(C.g0, C.w0) AG_A(C.g1, C.w1) AG_A(C.g2, C.w2) AG_A(C.g3, C.w3)
#undef AG_A
}

template<int IOBF>
__global__ void aggregate_kernel(void* __restrict__ iov,
                                 const unsigned short* __restrict__ msgAll,
                                 const int* __restrict__ off,
                                 const int2* __restrict__ edges,
                                 const int do_elu) {
    __shared__ int2 eq[1024];
    const int wid  = threadIdx.x >> 6;
    const int lane = threadIdx.x & 63;
    const int p0   = blockIdx.x * 4;
    const int sAll = (p0 == 0) ? 0 : off[p0 - 1];
    const int tot  = off[p0 + 3] - sAll;
    const bool fits = (tot <= 1024);
    if (fits)
        for (int i = threadIdx.x; i < tot; i += 256) eq[i] = edges[sAll + i];
    __syncthreads();

    const int p = p0 + wid;
    const int s = (p == 0) ? 0 : off[p - 1];
    const int e = off[p];
    const int n = e - s;

    float4 acc;
    if constexpr (IOBF) {
        const ushort4 t = ((const ushort4*)((const unsigned short*)iov + (size_t)p * Hd))[lane];
        acc = make_float4(b2f(t.x), b2f(t.y), b2f(t.z), b2f(t.w));
    } else {
        acc = ((const float4*)((const float*)iov + (size_t)p * Hd))[lane];
    }

    if (n > 0) {
        if (fits) {
            const int2* eqw = eq + (s - sAll);
            int nc = (n + 3) >> 2;
            nc += (nc & 1);                       // even, >= 2
            AgChunk CA, CB;
            ag_issue(eqw, 0, n, msgAll, lane, CA);
            int c = 1;
            for (; c + 1 < nc; c += 2) {
                ag_issue(eqw, 4 * c, n, msgAll, lane, CB);
                ag_acc(CA, acc);
                ag_issue(eqw, 4 * (c + 1), n, msgAll, lane, CA);
                ag_acc(CB, acc);
            }
            ag_issue(eqw, 4 * (nc - 1), n, msgAll, lane, CB);
            ag_acc(CA, acc);
            ag_acc(CB, acc);
        } else {
            for (int i = s; i < e; ++i) {
                const int2 ee = edges[i];
                const ushort4 g = ((const ushort4*)(msgAll + (size_t)ee.x * Hd))[lane];
                const float w = __int_as_float(ee.y);
                acc.x = fmaf(w, b2f(g.x), acc.x); acc.y = fmaf(w, b2f(g.y), acc.y);
                acc.z = fmaf(w, b2f(g.z), acc.z); acc.w = fmaf(w, b2f(g.w), acc.w);
            }
        }
    }
    if (do_elu) {
        acc.x = acc.x > 0.f ? acc.x : expm1f(acc.x);
        acc.y = acc.y > 0.f ? acc.y : expm1f(acc.y);
        acc.z = acc.z > 0.f ? acc.z : expm1f(acc.z);
        acc.w = acc.w > 0.f ? acc.w : expm1f(acc.w);
    }
    if constexpr (IOBF) {
        ((ushort4*)((unsigned short*)iov + (size_t)p * Hd))[lane] =
            make_ushort4(f2b(acc.x), f2b(acc.y), f2b(acc.z), f2b(acc.w));
    } else {
        ((float4*)((float*)iov + (size_t)p * Hd))[lane] = acc;
    }
}

extern "C" void kernel_launch(void* const* d_in, const int* in_sizes, int n_in,
                              void* d_out, int out_size, void* d_ws, size_t ws_size,
                              hipStream_t stream) {
    const float* pf    = (const float*)d_in[0];
    const float* ae    = (const float*)d_in[1];
    const int*   wsrc  = (const int*)d_in[2];
    const int*   wdst  = (const int*)d_in[3];
    const float* ww    = (const float*)d_in[4];
    const int*   csrc  = (const int*)d_in[5];
    const int*   cdst  = (const int*)d_in[6];
    const float* cw    = (const float*)d_in[7];
    const float* W1sp  = (const float*)d_in[8];
    const float* b1sp  = (const float*)d_in[9];
    const float* W1sa  = (const float*)d_in[10];
    const float* b1sa  = (const float*)d_in[11];
    const float* W1rw  = (const float*)d_in[12];
    const float* b1rw  = (const float*)d_in[13];
    const float* W1rc  = (const float*)d_in[14];
    const float* b1rc  = (const float*)d_in[15];
    const float* W2sp  = (const float*)d_in[16];
    const float* b2sp  = (const float*)d_in[17];
    const float* W2sa  = (const float*)d_in[18];
    const float* b2sa  = (const float*)d_in[19];
    const float* W2rw  = (const float*)d_in[20];
    const float* b2rw  = (const float*)d_in[21];
    const float* W2rc  = (const float*)d_in[22];
    const float* b2rc  = (const float*)d_in[23];

    const int E_W = in_sizes[2];
    const int E_C = in_sizes[5];

    float* outP = (float*)d_out;                        // [N_P, 256] fp32
    float* outA = outP + (size_t)N_P * Hd;              // [N_A, 256] fp32

    // Workspace layout:
    // xa1 f32[N_A*256] | xp1b u16[N_P*256] | msgAll u16[(N_A+N_P)*256] |
    // off[N_P] | edges int2[E] | bsum[256] | bc1 bcA2 bcP2 bcP1 f32[512 each] |
    // w1h w1l | wA2h wA2l | wP2m | wP1h
    float*          xa1    = (float*)d_ws;
    unsigned short* xp1b   = (unsigned short*)(xa1 + (size_t)N_A * Hd);
    unsigned short* msgAll = xp1b + (size_t)N_P * Hd;
    unsigned short* msgP   = msgAll + (size_t)N_A * Hd;
    int*            off    = (int*)(msgAll + (size_t)(N_A + N_P) * Hd);
    int2*           edges  = (int2*)(off + N_P);
    int*            bsum   = (int*)(edges + (E_W + E_C));
    float*          bc1    = (float*)(bsum + 256);
    float*          bcA2   = bc1 + 512;
    float*          bcP2   = bcA2 + 512;
    float*          bcP1   = bcP2 + 512;
    unsigned short* w1h    = (unsigned short*)(bcP1 + 512);
    unsigned short* w1l    = w1h  + (size_t)128 * 512;
    unsigned short* wA2h   = w1l  + (size_t)128 * 512;
    unsigned short* wA2l   = wA2h + (size_t)256 * 512;
    unsigned short* wP2m   = wA2l + (size_t)256 * 512;   // 512*512 shorts
    unsigned short* wP1h   = wP2m + (size_t)512 * 512;

    const dim3 blk(256);
    const int  nb = (N_P + 1023) / 1024;      // 98
    const int  gP = (N_P + 63) / 64;          // 1563 (last block partial)

    // ---------------- prep ----------------
    prep_kernel<<<1440, 64, 0, stream>>>(W1sa, W1rw, W2sa, W2rw, W2rc, W2sp, W1sp, W1rc,
                                         b1sa, b1rw, b2sa, b2rw, b2rc, b2sp, b1sp, b1rc,
                                         w1h, w1l, wA2h, wA2l, wP2m, wP1h,
                                         bc1, bcA2, bcP2, bcP1);

    // ---------------- combined CSR ----------------
    hipMemsetAsync(off, 0, (size_t)N_P * sizeof(int), stream);
    hist_kernel<<<1024, blk, 0, stream>>>(wdst, E_W, cdst, E_C, off);
    scan1_kernel<<<nb, blk, 0, stream>>>(off, N_P, bsum);
    scan2_kernel<<<1,  blk, 0, stream>>>(bsum, nb);
    scan3_kernel<<<(N_P + 255) / 256, blk, 0, stream>>>(off, N_P, bsum);
    fill_kernel<<<1024, blk, 0, stream>>>(wsrc, wdst, ww, E_W, csrc, cdst, cw, E_C,
                                          off, edges);

    // ---------------- Layer 1 ----------------
    // paper self + cites msg: streamed mono GEMM over binary pf (K=512)
    mfma_stream_kernel<0><<<gP, blk, 64 * 512 * 2, stream>>>(pf, 512, 16, 1, wP1h, bcP1,
                                                             xp1b, msgP, 1, 1, 0, 0, N_P);
    // author self (ELU, fp32 xa1) + writes msg (bf16 into msgAll)
    mfma_dual_kernel<<<N_A / 32, blk, 32 * 128 * 4, stream>>>(ae, 128, w1h, w1l, bc1,
                                                              xa1, msgAll, 1, 0, 0, 1);
    aggregate_kernel<1><<<N_P / 4, blk, 0, stream>>>(xp1b, msgAll, off, edges, 1);

    // ---------------- Layer 2 ----------------
    mfma_dual_kernel<<<N_A / 32, blk, 32 * 256 * 4, stream>>>(xa1, 256, wA2h, wA2l, bcA2,
                                                              outA, msgAll, 0, 0, 0, 1);
    // paper: A = xp1b (bf16), interleaved hi/lo B (K_eff=512, exact 2-product)
    mfma_stream_kernel<1><<<gP, blk, 64 * 256 * 2, stream>>>(xp1b, 256, 16, 2, wP2m, bcP2,
                                                             msgP, outP, 1, 0, 0, 0, N_P);
    aggregate_kernel<0><<<N_P / 4, blk, 0, stream>>>(outP, msgAll, off, edges, 0);
}

// Round 15
// 504.858 us; speedup vs baseline: 1.2446x; 1.2427x over previous
//
#include <hip/hip_runtime.h>
#include <cstdint>
#include <cstddef>

constexpr int Hd  = 256;
constexpr int N_P = 100000;
constexpr int N_A = 20000;
constexpr int F_P = 512;
constexpr int D_A = 128;

typedef short bf16x8 __attribute__((ext_vector_type(8)));
typedef float f32x4  __attribute__((ext_vector_type(4)));

// fp32 -> bf16 round-to-nearest-even
__device__ __forceinline__ unsigned short f2b(float x) {
    unsigned u = __float_as_uint(x);
    u += 0x7fffu + ((u >> 16) & 1u);
    return (unsigned short)(u >> 16);
}
__device__ __forceinline__ float b2f(unsigned short h) {
    return __uint_as_float((unsigned)h << 16);
}
// pack two fp32 (truncated) into one u32 of 2 bf16 (lo, hi)
__device__ __forceinline__ unsigned pk2(float lo, float hi) {
    return (__float_as_uint(lo) >> 16) | (__float_as_uint(hi) & 0xffff0000u);
}

// split fp32 into bf16 hi + bf16 lo (truncation; combined error ~2^-16 rel)
__device__ __forceinline__ void bsplit(float x, unsigned short& hi, unsigned short& lo) {
    const unsigned u = __float_as_uint(x);
    hi = (unsigned short)(u >> 16);
    const float r = x - __uint_as_float(u & 0xffff0000u);
    lo = (unsigned short)(__float_as_uint(r) >> 16);
}

// ---------------------------------------------------------------------------
// prep: pack W tables into MFMA B-fragment layout + bias concats.
//  blocks [0,128):    (W1sa|W1rw) K=128, bf16 hi/lo (author L1, 3-product)
//  blocks [128,384):  (W2sa|W2rw) K=256, bf16 hi/lo (author L2, 3-product)
//  blocks [384,640):  (W2rc|W2sp) K=256, bf16 RNE single (paper L2, 1-product)
//  blocks [640,1152): (W1sp|W1rc) K=512, bf16 RNE single (paper L1, 1-product)
//  blocks [1152,1184): bias concats bc1, bcA2, bcP2, bcP1
// ---------------------------------------------------------------------------
__global__ void prep_kernel(const float* __restrict__ W1sa, const float* __restrict__ W1rw,
                            const float* __restrict__ W2sa, const float* __restrict__ W2rw,
                            const float* __restrict__ W2rc, const float* __restrict__ W2sp,
                            const float* __restrict__ W1sp, const float* __restrict__ W1rc,
                            const float* __restrict__ b1sa, const float* __restrict__ b1rw,
                            const float* __restrict__ b2sa, const float* __restrict__ b2rw,
                            const float* __restrict__ b2rc, const float* __restrict__ b2sp,
                            const float* __restrict__ b1sp, const float* __restrict__ b1rc,
                            unsigned short* __restrict__ w1h,  unsigned short* __restrict__ w1l,
                            unsigned short* __restrict__ wA2h, unsigned short* __restrict__ wA2l,
                            unsigned short* __restrict__ wP2h,
                            unsigned short* __restrict__ wP1h,
                            float* __restrict__ bc1, float* __restrict__ bcA2,
                            float* __restrict__ bcP2, float* __restrict__ bcP1) {
    const int b = blockIdx.x;
    const int l = threadIdx.x;
    if (b < 384) {
        const float *Wa, *Wb; unsigned short *wh, *wl; int rel;
        if (b < 128) { Wa = W1sa; Wb = W1rw; wh = w1h;  wl = w1l;  rel = b; }
        else         { Wa = W2sa; Wb = W2rw; wh = wA2h; wl = wA2l; rel = b - 128; }
        const int ks  = rel >> 5;
        const int nfg = rel & 31;
        const float* W = (nfg < 16) ? Wa : Wb;
        const int col  = (nfg & 15) * 16 + (l & 15);
        const size_t base = ((size_t)rel * 64 + l) * 8;
        #pragma unroll
        for (int j = 0; j < 8; ++j) {
            const int k = ks * 32 + ((l >> 4) * 8) + j;
            unsigned short h, lw;
            bsplit(W[(size_t)k * Hd + col], h, lw);
            wh[base + j] = h;
            wl[base + j] = lw;
        }
    } else if (b < 640) {
        const int rel = b - 384;                  // [0,256)
        const int ks  = rel >> 5;
        const int nfg = rel & 31;
        const float* W = (nfg < 16) ? W2rc : W2sp;
        const int col  = (nfg & 15) * 16 + (l & 15);
        const size_t base = ((size_t)rel * 64 + l) * 8;
        #pragma unroll
        for (int j = 0; j < 8; ++j) {
            const int k = ks * 32 + ((l >> 4) * 8) + j;
            wP2h[base + j] = f2b(W[(size_t)k * Hd + col]);
        }
    } else if (b < 1152) {
        const int rel = b - 640;                  // [0,512)
        const int ks  = rel >> 5;
        const int nfg = rel & 31;
        const float* W = (nfg < 16) ? W1sp : W1rc;
        const int col  = (nfg & 15) * 16 + (l & 15);
        const size_t base = ((size_t)rel * 64 + l) * 8;
        #pragma unroll
        for (int j = 0; j < 8; ++j) {
            const int k = ks * 32 + ((l >> 4) * 8) + j;
            wP1h[base + j] = f2b(W[(size_t)k * Hd + col]);
        }
    } else {
        const int t     = (b - 1152) * 64 + l;    // 0..2047
        const int which = t >> 9;
        const int idx   = t & 511;
        const float* src; float* dst;
        if (which == 0)      { src = (idx < 256) ? b1sa : b1rw; dst = bc1;  }
        else if (which == 1) { src = (idx < 256) ? b2sa : b2rw; dst = bcA2; }
        else if (which == 2) { src = (idx < 256) ? b2rc : b2sp; dst = bcP2; }
        else                 { src = (idx < 256) ? b1sp : b1rc; dst = bcP1; }
        dst[idx] = src[idx & 255];
    }
}

// ---------------------------------------------------------------------------
// TILE MFMA GEMM (m93/m97-style, both operands LDS-staged, 1-product bf16):
// 128 rows x 128 cols per block (grid = gM x 4 col-blocks), BK=32, 4 waves,
// wave (wr,wc) owns 64x64 (acc[4][4]). Per K-step, single-barrier double
// buffer: A-tile (128x32) reg-staged into FRAGMENT-layout LDS (2 linear 16B
// entries/thread, conflict-free); B-tile = contiguous 8KB memcpy from the
// fragment-packed W table (2x16B/thread). T14: next-step global loads issue
// BEFORE the MFMA burst, ds_writes after. Fragments read via linear
// ds_read_b128 (conflict-free).
//  ASRC=0: fp32 A truncated to bf16 (EXACT for binary pf); ASRC=1: bf16 A.
// ---------------------------------------------------------------------------
template<int ASRC>
__global__ void __launch_bounds__(256, 3)
mfma_tile_kernel(const void* __restrict__ Av, const int KA, const int nks,
                 const unsigned short* __restrict__ wtab,
                 const float* __restrict__ bcat,
                 void* __restrict__ Oa, void* __restrict__ Ob,
                 const int bfA, const int bfB, const int Mtot) {
    extern __shared__ char smem[];                 // [2][ A:8KB | B:8KB ]
    const int tid = threadIdx.x;
    const int wid = tid >> 6;
    const int l   = tid & 63;
    const int c   = blockIdx.x & 3;                // col-block (128 cols)
    const long m0 = (long)(blockIdx.x >> 2) * 128;
    const int wr  = wid >> 1, wc = wid & 1;

    // A staging geometry: entry e in [0,512): frag f=e>>6, lane le=e&63
    // holds A[f*16 + (le&15)][ks*32 + (le>>4)*8 + j], j=0..7 (16B), at e*16.
    const int f0 = tid >> 6;                       // entries tid and tid+256
    const int le = tid & 63;
    long grow0 = m0 + f0 * 16 + (le & 15);       if (grow0 > Mtot - 1) grow0 = Mtot - 1;
    long grow1 = m0 + (f0 + 4) * 16 + (le & 15); if (grow1 > Mtot - 1) grow1 = Mtot - 1;
    const int kg = (le >> 4) * 8;                  // k offset within 32-slice

    // staging registers (named; rule-20 safe)
    float4 a00, a01, a10, a11;                     // ASRC=0
    uint4  ua0, ua1;                               // ASRC=1
    uint4  ub0, ub1;                               // B copy

#define TK_LOAD(KS) { \
    if constexpr (ASRC == 0) { \
        const float* A = (const float*)Av; \
        const float* p0_ = A + grow0 * KA + (KS) * 32 + kg; \
        const float* p1_ = A + grow1 * KA + (KS) * 32 + kg; \
        a00 = *(const float4*)p0_; a01 = *(const float4*)(p0_ + 4); \
        a10 = *(const float4*)p1_; a11 = *(const float4*)(p1_ + 4); \
    } else { \
        const unsigned short* A = (const unsigned short*)Av; \
        ua0 = *(const uint4*)(A + grow0 * KA + (KS) * 32 + kg); \
        ua1 = *(const uint4*)(A + grow1 * KA + (KS) * 32 + kg); \
    } \
    { const unsigned short* bs_ = wtab + ((size_t)((KS) * 32 + c * 8) * 512) + tid * 16; \
      ub0 = *(const uint4*)bs_; ub1 = *(const uint4*)(bs_ + 8); } }

#define TK_WRITE(BUF) { \
    char* Ab_ = smem + (BUF) * 16384; \
    char* Bb_ = Ab_ + 8192; \
    if constexpr (ASRC == 0) { \
        *(uint4*)(Ab_ + tid * 16) = make_uint4(pk2(a00.x, a00.y), pk2(a00.z, a00.w), \
                                               pk2(a01.x, a01.y), pk2(a01.z, a01.w)); \
        *(uint4*)(Ab_ + (tid + 256) * 16) = make_uint4(pk2(a10.x, a10.y), pk2(a10.z, a10.w), \
                                                       pk2(a11.x, a11.y), pk2(a11.z, a11.w)); \
    } else { \
        *(uint4*)(Ab_ + tid * 16) = ua0; \
        *(uint4*)(Ab_ + (tid + 256) * 16) = ua1; \
    } \
    *(uint4*)(Bb_ + tid * 32) = ub0; \
    *(uint4*)(Bb_ + tid * 32 + 16) = ub1; }

    // ---- accumulators, bias init (bias depends only on col) ----
    f32x4 acc[4][4];
    #pragma unroll
    for (int nf = 0; nf < 4; ++nf) {
        const float b = bcat[c * 128 + wc * 64 + nf * 16 + (l & 15)];
        #pragma unroll
        for (int mf = 0; mf < 4; ++mf) acc[mf][nf] = (f32x4){b, b, b, b};
    }

    // ---- prologue ----
    TK_LOAD(0)
    TK_WRITE(0)
    __syncthreads();

    int cur = 0;
    for (int ks = 0; ks < nks; ++ks) {
        const bool more = (ks + 1 < nks);
        if (more) TK_LOAD(ks + 1)                  // issue early (T14)
        // compute from buf[cur]
        {
            const char* Ab = smem + cur * 16384;
            const char* Bb = Ab + 8192;
            bf16x8 af[4], bfv[4];
            #pragma unroll
            for (int mf = 0; mf < 4; ++mf)
                af[mf] = *(const bf16x8*)(Ab + ((wr * 4 + mf) * 64 + l) * 16);
            #pragma unroll
            for (int nf = 0; nf < 4; ++nf)
                bfv[nf] = *(const bf16x8*)(Bb + ((wc * 4 + nf) * 64 + l) * 16);
            #pragma unroll
            for (int nf = 0; nf < 4; ++nf) {
                #pragma unroll
                for (int mf = 0; mf < 4; ++mf)
                    acc[mf][nf] = __builtin_amdgcn_mfma_f32_16x16x32_bf16(af[mf], bfv[nf], acc[mf][nf], 0, 0, 0);
            }
        }
        if (more) TK_WRITE(cur ^ 1)                // write late
        __syncthreads();
        cur ^= 1;
    }
#undef TK_LOAD
#undef TK_WRITE

    // ---- epilogue (col-block uniform output select, guarded rows) ----
    #pragma unroll
    for (int mf = 0; mf < 4; ++mf) {
        #pragma unroll
        for (int nf = 0; nf < 4; ++nf) {
            const int gcol = c * 128 + wc * 64 + nf * 16 + (l & 15);
            void* O; int col, isbf;
            if (gcol < 256) { O = Oa; col = gcol;       isbf = bfA; }
            else            { O = Ob; col = gcol - 256; isbf = bfB; }
            const long row = m0 + wr * 64 + mf * 16 + ((l >> 4) * 4);
            const f32x4 v = acc[mf][nf];
            #pragma unroll
            for (int r = 0; r < 4; ++r) {
                if (row + r < Mtot) {
                    const float x = v[r];
                    if (isbf) ((unsigned short*)O)[(row + r) * Hd + col] = f2b(x);
                    else      ((float*)O)[(row + r) * Hd + col] = x;
                }
            }
        }
    }
}

// ---------------------------------------------------------------------------
// Dual-output MFMA GEMM (author GEMMs only): fp32 A, split-bf16 3-product.
// 32 rows/block. Proven R7 structure, unchanged.
// ---------------------------------------------------------------------------
__global__ void mfma_dual_kernel(const void* __restrict__ Av, const int K,
                                 const unsigned short* __restrict__ whi,
                                 const unsigned short* __restrict__ wlo,
                                 const float* __restrict__ bcat,
                                 void* __restrict__ Oa, void* __restrict__ Ob,
                                 const int actA, const int actB,
                                 const int bfA, const int bfB) {
    extern __shared__ char smem[];
    char* sh = smem;
    char* sl = smem + 32 * K * 2;
    const int  tid = threadIdx.x;
    const int  wid = tid >> 6;
    const int  l   = tid & 63;
    const long m0  = (long)blockIdx.x * 32;
    const int  rowStride = 2 * K;

    const int kq4 = K >> 2;
    const float* A = (const float*)Av;
    for (int i = tid; i < 32 * kq4; i += 256) {
        const int row = i / kq4;
        const int kq  = i - row * kq4;
        const float4 v = *(const float4*)(A + (m0 + row) * K + kq * 4);
        unsigned short h0, h1, h2, h3, l0, l1, l2, l3;
        bsplit(v.x, h0, l0); bsplit(v.y, h1, l1);
        bsplit(v.z, h2, l2); bsplit(v.w, h3, l3);
        const int ofs = row * rowStride + ((kq * 8) ^ ((row & 7) << 4));
        *(ushort4*)(sh + ofs) = make_ushort4(h0, h1, h2, h3);
        *(ushort4*)(sl + ofs) = make_ushort4(l0, l1, l2, l3);
    }
    __syncthreads();

    f32x4 acc[2][8];
    #pragma unroll
    for (int nf = 0; nf < 8; ++nf) {
        const float b = bcat[wid * 128 + nf * 16 + (l & 15)];
        acc[0][nf] = (f32x4){b, b, b, b};
        acc[1][nf] = (f32x4){b, b, b, b};
    }

    const int kb  = (l >> 4) * 16;
    const int r0  = l & 15;
    const int r1  = 16 + r0;
    const int sw  = (l & 7) << 4;
    const int ro0 = r0 * rowStride;
    const int ro1 = r1 * rowStride;
    for (int ks = 0; ks < (K >> 5); ++ks) {
        const int bk = (ks * 64 + kb) ^ sw;
        const bf16x8 ah0 = *(const bf16x8*)(sh + ro0 + bk);
        const bf16x8 ah1 = *(const bf16x8*)(sh + ro1 + bk);
        const bf16x8 al0 = *(const bf16x8*)(sl + ro0 + bk);
        const bf16x8 al1 = *(const bf16x8*)(sl + ro1 + bk);
        const size_t wbase = (((size_t)ks * 32 + wid * 8) * 64 + l) * 8;
        #pragma unroll
        for (int nf = 0; nf < 8; ++nf) {
            const bf16x8 bh = *(const bf16x8*)(whi + wbase + (size_t)nf * 512);
            const bf16x8 bl = *(const bf16x8*)(wlo + wbase + (size_t)nf * 512);
            acc[0][nf] = __builtin_amdgcn_mfma_f32_16x16x32_bf16(ah0, bh, acc[0][nf], 0, 0, 0);
            acc[1][nf] = __builtin_amdgcn_mfma_f32_16x16x32_bf16(ah1, bh, acc[1][nf], 0, 0, 0);
            acc[0][nf] = __builtin_amdgcn_mfma_f32_16x16x32_bf16(al0, bh, acc[0][nf], 0, 0, 0);
            acc[1][nf] = __builtin_amdgcn_mfma_f32_16x16x32_bf16(al1, bh, acc[1][nf], 0, 0, 0);
            acc[0][nf] = __builtin_amdgcn_mfma_f32_16x16x32_bf16(ah0, bl, acc[0][nf], 0, 0, 0);
            acc[1][nf] = __builtin_amdgcn_mfma_f32_16x16x32_bf16(ah1, bl, acc[1][nf], 0, 0, 0);
        }
    }

    #pragma unroll
    for (int mf = 0; mf < 2; ++mf) {
        #pragma unroll
        for (int nf = 0; nf < 8; ++nf) {
            const int colg = wid * 128 + nf * 16 + (l & 15);
            void* O;
            int col, act, isbf;
            if (colg < 256) { O = Oa; col = colg;       act = actA; isbf = bfA; }
            else            { O = Ob; col = colg - 256; act = actB; isbf = bfB; }
            const long row = m0 + mf * 16 + ((l >> 4) * 4);
            const f32x4 v = acc[mf][nf];
            #pragma unroll
            for (int r = 0; r < 4; ++r) {
                float x = v[r];
                if (act) x = x > 0.f ? x : expm1f(x);
                if (isbf) ((unsigned short*)O)[(row + r) * Hd + col] = f2b(x);
                else      ((float*)O)[(row + r) * Hd + col] = x;
            }
        }
    }
}

// ---------------------------------------------------------------------------
// Combined-relation CSR build. src' = writes ? wsrc : N_A + csrc.
// After fill, off[p] = END of segment p.
// ---------------------------------------------------------------------------
__global__ void hist_kernel(const int* __restrict__ wdst, const int EW,
                            const int* __restrict__ cdst, const int EC,
                            int* __restrict__ cnt) {
    for (int i = blockIdx.x * blockDim.x + threadIdx.x; i < EW + EC; i += gridDim.x * blockDim.x) {
        const int d = (i < EW) ? wdst[i] : cdst[i - EW];
        atomicAdd(&cnt[d], 1);
    }
}

__global__ void scan1_kernel(int* __restrict__ data, const int n, int* __restrict__ bsum) {
    __shared__ int s[256];
    const int t = threadIdx.x;
    const int base = blockIdx.x * 1024 + t * 4;
    int v0 = (base + 0 < n) ? data[base + 0] : 0;
    int v1 = (base + 1 < n) ? data[base + 1] : 0;
    int v2 = (base + 2 < n) ? data[base + 2] : 0;
    int v3 = (base + 3 < n) ? data[base + 3] : 0;
    const int tsum = v0 + v1 + v2 + v3;
    s[t] = tsum;
    __syncthreads();
    for (int off = 1; off < 256; off <<= 1) {
        int y = (t >= off) ? s[t - off] : 0;
        __syncthreads();
        if (t >= off) s[t] += y;
        __syncthreads();
    }
    const int e = s[t] - tsum;
    if (base + 0 < n) data[base + 0] = e;
    if (base + 1 < n) data[base + 1] = e + v0;
    if (base + 2 < n) data[base + 2] = e + v0 + v1;
    if (base + 3 < n) data[base + 3] = e + v0 + v1 + v2;
    if (t == 255) bsum[blockIdx.x] = s[255];
}

__global__ void scan2_kernel(int* __restrict__ bsum, const int nb) {
    __shared__ int s[256];
    const int t = threadIdx.x;
    const int v = (t < nb) ? bsum[t] : 0;
    s[t] = v;
    __syncthreads();
    for (int off = 1; off < 256; off <<= 1) {
        int y = (t >= off) ? s[t - off] : 0;
        __syncthreads();
        if (t >= off) s[t] += y;
        __syncthreads();
    }
    if (t < nb) bsum[t] = s[t] - v;
}

__global__ void scan3_kernel(int* __restrict__ data, const int n, const int* __restrict__ bsum) {
    const int i = blockIdx.x * blockDim.x + threadIdx.x;
    if (i < n) data[i] += bsum[i >> 10];
}

__global__ void fill_kernel(const int* __restrict__ wsrc, const int* __restrict__ wdst,
                            const float* __restrict__ ww, const int EW,
                            const int* __restrict__ csrc, const int* __restrict__ cdst,
                            const float* __restrict__ cw, const int EC,
                            int* __restrict__ cur, int2* __restrict__ edges) {
    for (int i = blockIdx.x * blockDim.x + threadIdx.x; i < EW + EC; i += gridDim.x * blockDim.x) {
        int d, sp; float w;
        if (i < EW) { d = wdst[i]; sp = wsrc[i]; w = ww[i]; }
        else        { const int j = i - EW; d = cdst[j]; sp = N_A + csrc[j]; w = cw[j]; }
        const int p = atomicAdd(&cur[d], 1);
        edges[p] = make_int2(sp, __float_as_int(w));
    }
}

// ---------------------------------------------------------------------------
// Pull aggregation (R7-proven version). Block = 4 dests (1 per wave). Block
// stages its 4 dests' contiguous edge window into LDS eq[1024]; chunk-4 A/B
// ping-pong per wave. Serial fallback for >1024-edge windows.
// IOBF: io bf16 (layer 1) or fp32 (layer 2).
// ---------------------------------------------------------------------------
struct AgChunk { ushort4 g0, g1, g2, g3; float w0, w1, w2, w3; };

__device__ __forceinline__ void ag_issue(const int2* __restrict__ eq, const int base, const int n,
                                         const unsigned short* __restrict__ msg,
                                         const int lane, AgChunk& C) {
#define AG_ONE(J, GG, WW) { \
    const int idx = base + (J); \
    const int2 ee = eq[min(idx, n - 1)]; \
    WW = (idx < n) ? __int_as_float(ee.y) : 0.f; \
    GG = ((const ushort4*)(msg + (size_t)ee.x * Hd))[lane]; }
    AG_ONE(0, C.g0, C.w0)
    AG_ONE(1, C.g1, C.w1)
    AG_ONE(2, C.g2, C.w2)
    AG_ONE(3, C.g3, C.w3)
#undef AG_ONE
}

__device__ __forceinline__ void ag_acc(const AgChunk& C, float4& acc) {
#define AG_A(GG, WW) { \
    acc.x = fmaf(WW, b2f(GG.x), acc.x); acc.y = fmaf(WW, b2f(GG.y), acc.y); \
    acc.z = fmaf(WW, b2f(GG.z), acc.z); acc.w = fmaf(WW, b2f(GG.w), acc.w); }
    AG_A(C.g0, C.w0) AG_A(C.g1, C.w1) AG_A(C.g2, C.w2) AG_A(C.g3, C.w3)
#undef AG_A
}

template<int IOBF>
__global__ void aggregate_kernel(void* __restrict__ iov,
                                 const unsigned short* __restrict__ msgAll,
                                 const int* __restrict__ off,
                                 const int2* __restrict__ edges,
                                 const int do_elu) {
    __shared__ int2 eq[1024];
    const int wid  = threadIdx.x >> 6;
    const int lane = threadIdx.x & 63;
    const int p0   = blockIdx.x * 4;
    const int sAll = (p0 == 0) ? 0 : off[p0 - 1];
    const int tot  = off[p0 + 3] - sAll;
    const bool fits = (tot <= 1024);
    if (fits)
        for (int i = threadIdx.x; i < tot; i += 256) eq[i] = edges[sAll + i];
    __syncthreads();

    const int p = p0 + wid;
    const int s = (p == 0) ? 0 : off[p - 1];
    const int e = off[p];
    const int n = e - s;

    float4 acc;
    if constexpr (IOBF) {
        const ushort4 t = ((const ushort4*)((const unsigned short*)iov + (size_t)p * Hd))[lane];
        acc = make_float4(b2f(t.x), b2f(t.y), b2f(t.z), b2f(t.w));
    } else {
        acc = ((const float4*)((const float*)iov + (size_t)p * Hd))[lane];
    }

    if (n > 0) {
        if (fits) {
            const int2* eqw = eq + (s - sAll);
            int nc = (n + 3) >> 2;
            nc += (nc & 1);                       // even, >= 2
            AgChunk CA, CB;
            ag_issue(eqw, 0, n, msgAll, lane, CA);
            int c = 1;
            for (; c + 1 < nc; c += 2) {
                ag_issue(eqw, 4 * c, n, msgAll, lane, CB);
                ag_acc(CA, acc);
                ag_issue(eqw, 4 * (c + 1), n, msgAll, lane, CA);
                ag_acc(CB, acc);
            }
            ag_issue(eqw, 4 * (nc - 1), n, msgAll, lane, CB);
            ag_acc(CA, acc);
            ag_acc(CB, acc);
        } else {
            for (int i = s; i < e; ++i) {
                const int2 ee = edges[i];
                const ushort4 g = ((const ushort4*)(msgAll + (size_t)ee.x * Hd))[lane];
                const float w = __int_as_float(ee.y);
                acc.x = fmaf(w, b2f(g.x), acc.x); acc.y = fmaf(w, b2f(g.y), acc.y);
                acc.z = fmaf(w, b2f(g.z), acc.z); acc.w = fmaf(w, b2f(g.w), acc.w);
            }
        }
    }
    if (do_elu) {
        acc.x = acc.x > 0.f ? acc.x : expm1f(acc.x);
        acc.y = acc.y > 0.f ? acc.y : expm1f(acc.y);
        acc.z = acc.z > 0.f ? acc.z : expm1f(acc.z);
        acc.w = acc.w > 0.f ? acc.w : expm1f(acc.w);
    }
    if constexpr (IOBF) {
        ((ushort4*)((unsigned short*)iov + (size_t)p * Hd))[lane] =
            make_ushort4(f2b(acc.x), f2b(acc.y), f2b(acc.z), f2b(acc.w));
    } else {
        ((float4*)((float*)iov + (size_t)p * Hd))[lane] = acc;
    }
}

extern "C" void kernel_launch(void* const* d_in, const int* in_sizes, int n_in,
                              void* d_out, int out_size, void* d_ws, size_t ws_size,
                              hipStream_t stream) {
    const float* pf    = (const float*)d_in[0];
    const float* ae    = (const float*)d_in[1];
    const int*   wsrc  = (const int*)d_in[2];
    const int*   wdst  = (const int*)d_in[3];
    const float* ww    = (const float*)d_in[4];
    const int*   csrc  = (const int*)d_in[5];
    const int*   cdst  = (const int*)d_in[6];
    const float* cw    = (const float*)d_in[7];
    const float* W1sp  = (const float*)d_in[8];
    const float* b1sp  = (const float*)d_in[9];
    const float* W1sa  = (const float*)d_in[10];
    const float* b1sa  = (const float*)d_in[11];
    const float* W1rw  = (const float*)d_in[12];
    const float* b1rw  = (const float*)d_in[13];
    const float* W1rc  = (const float*)d_in[14];
    const float* b1rc  = (const float*)d_in[15];
    const float* W2sp  = (const float*)d_in[16];
    const float* b2sp  = (const float*)d_in[17];
    const float* W2sa  = (const float*)d_in[18];
    const float* b2sa  = (const float*)d_in[19];
    const float* W2rw  = (const float*)d_in[20];
    const float* b2rw  = (const float*)d_in[21];
    const float* W2rc  = (const float*)d_in[22];
    const float* b2rc  = (const float*)d_in[23];

    const int E_W = in_sizes[2];
    const int E_C = in_sizes[5];

    float* outP = (float*)d_out;                        // [N_P, 256] fp32
    float* outA = outP + (size_t)N_P * Hd;              // [N_A, 256] fp32

    // Workspace layout:
    // xa1 f32[N_A*256] | xp1b u16[N_P*256] | msgAll u16[(N_A+N_P)*256] |
    // off[N_P] | edges int2[E] | bsum[256] | bc1 bcA2 bcP2 bcP1 f32[512 each] |
    // w1h w1l | wA2h wA2l | wP2h | wP1h
    float*          xa1    = (float*)d_ws;
    unsigned short* xp1b   = (unsigned short*)(xa1 + (size_t)N_A * Hd);
    unsigned short* msgAll = xp1b + (size_t)N_P * Hd;
    unsigned short* msgP   = msgAll + (size_t)N_A * Hd;
    int*            off    = (int*)(msgAll + (size_t)(N_A + N_P) * Hd);
    int2*           edges  = (int2*)(off + N_P);
    int*            bsum   = (int*)(edges + (E_W + E_C));
    float*          bc1    = (float*)(bsum + 256);
    float*          bcA2   = bc1 + 512;
    float*          bcP2   = bcA2 + 512;
    float*          bcP1   = bcP2 + 512;
    unsigned short* w1h    = (unsigned short*)(bcP1 + 512);
    unsigned short* w1l    = w1h  + (size_t)128 * 512;
    unsigned short* wA2h   = w1l  + (size_t)128 * 512;
    unsigned short* wA2l   = wA2h + (size_t)256 * 512;
    unsigned short* wP2h   = wA2l + (size_t)256 * 512;   // 256*512 shorts
    unsigned short* wP1h   = wP2h + (size_t)256 * 512;   // 512*512 shorts

    const dim3 blk(256);
    const int  nb  = (N_P + 1023) / 1024;     // 98
    const int  gM  = (N_P + 127) / 128;       // 782
    const int  gP  = gM * 4;                  // 4 col-blocks of 128

    // ---------------- prep ----------------
    prep_kernel<<<1184, 64, 0, stream>>>(W1sa, W1rw, W2sa, W2rw, W2rc, W2sp, W1sp, W1rc,
                                         b1sa, b1rw, b2sa, b2rw, b2rc, b2sp, b1sp, b1rc,
                                         w1h, w1l, wA2h, wA2l, wP2h, wP1h,
                                         bc1, bcA2, bcP2, bcP1);

    // ---------------- combined CSR ----------------
    hipMemsetAsync(off, 0, (size_t)N_P * sizeof(int), stream);
    hist_kernel<<<1024, blk, 0, stream>>>(wdst, E_W, cdst, E_C, off);
    scan1_kernel<<<nb, blk, 0, stream>>>(off, N_P, bsum);
    scan2_kernel<<<1,  blk, 0, stream>>>(bsum, nb);
    scan3_kernel<<<(N_P + 255) / 256, blk, 0, stream>>>(off, N_P, bsum);
    fill_kernel<<<1024, blk, 0, stream>>>(wsrc, wdst, ww, E_W, csrc, cdst, cw, E_C,
                                          off, edges);

    // ---------------- Layer 1 ----------------
    // paper self + cites msg: 128x128-tile LDS-staged GEMM over binary pf (K=512)
    mfma_tile_kernel<0><<<gP, blk, 32768, stream>>>(pf, 512, 16, wP1h, bcP1,
                                                    xp1b, msgP, 1, 1, N_P);
    // author self (ELU, fp32 xa1) + writes msg (bf16 into msgAll)
    mfma_dual_kernel<<<N_A / 32, blk, 32 * 128 * 4, stream>>>(ae, 128, w1h, w1l, bc1,
                                                              xa1, msgAll, 1, 0, 0, 1);
    aggregate_kernel<1><<<N_P / 4, blk, 0, stream>>>(xp1b, msgAll, off, edges, 1);

    // ---------------- Layer 2 ----------------
    mfma_dual_kernel<<<N_A / 32, blk, 32 * 256 * 4, stream>>>(xa1, 256, wA2h, wA2l, bcA2,
                                                              outA, msgAll, 0, 0, 0, 1);
    // paper: A = xp1b (bf16), B = RNE-bf16 (W2rc|W2sp) K=256, 1-product
    mfma_tile_kernel<1><<<gP, blk, 32768, stream>>>(xp1b, 256, 8, wP2h, bcP2,
                                                    msgP, outP, 1, 0, N_P);
    aggregate_kernel<0><<<N_P / 4, blk, 0, stream>>>(outP, msgAll, off, edges, 0);
}

// Round 16
// 476.229 us; speedup vs baseline: 1.3194x; 1.0601x over previous
//
#include <hip/hip_runtime.h>
#include <cstdint>
#include <cstddef>

constexpr int Hd  = 256;
constexpr int N_P = 100000;
constexpr int N_A = 20000;
constexpr int F_P = 512;
constexpr int D_A = 128;

typedef short bf16x8 __attribute__((ext_vector_type(8)));
typedef float f32x4  __attribute__((ext_vector_type(4)));

__device__ __forceinline__ unsigned short f2b(float x) {
    unsigned u = __float_as_uint(x);
    u += 0x7fffu + ((u >> 16) & 1u);
    return (unsigned short)(u >> 16);
}
__device__ __forceinline__ float b2f(unsigned short h) {
    return __uint_as_float((unsigned)h << 16);
}
__device__ __forceinline__ unsigned pk2(float lo, float hi) {
    return (__float_as_uint(lo) >> 16) | (__float_as_uint(hi) & 0xffff0000u);
}
__device__ __forceinline__ void bsplit(float x, unsigned short& hi, unsigned short& lo) {
    const unsigned u = __float_as_uint(x);
    hi = (unsigned short)(u >> 16);
    const float r = x - __uint_as_float(u & 0xffff0000u);
    lo = (unsigned short)(__float_as_uint(r) >> 16);
}

// async global->LDS, 16B per lane: LDS dest = wave-uniform base + lane*16,
// global src = per-lane address (m173 pre-swizzled-source pattern).
__device__ __forceinline__ void gld16(const void* g, void* l) {
    __builtin_amdgcn_global_load_lds(
        (const __attribute__((address_space(1))) unsigned int*)g,
        (__attribute__((address_space(3))) unsigned int*)l, 16, 0, 0);
}

// ---------------------------------------------------------------------------
// prep: pack W tables into MFMA B-fragment layout + bias concats. (R15 proven)
// ---------------------------------------------------------------------------
__global__ void prep_kernel(const float* __restrict__ W1sa, const float* __restrict__ W1rw,
                            const float* __restrict__ W2sa, const float* __restrict__ W2rw,
                            const float* __restrict__ W2rc, const float* __restrict__ W2sp,
                            const float* __restrict__ W1sp, const float* __restrict__ W1rc,
                            const float* __restrict__ b1sa, const float* __restrict__ b1rw,
                            const float* __restrict__ b2sa, const float* __restrict__ b2rw,
                            const float* __restrict__ b2rc, const float* __restrict__ b2sp,
                            const float* __restrict__ b1sp, const float* __restrict__ b1rc,
                            unsigned short* __restrict__ w1h,  unsigned short* __restrict__ w1l,
                            unsigned short* __restrict__ wA2h, unsigned short* __restrict__ wA2l,
                            unsigned short* __restrict__ wP2h,
                            unsigned short* __restrict__ wP1h,
                            float* __restrict__ bc1, float* __restrict__ bcA2,
                            float* __restrict__ bcP2, float* __restrict__ bcP1) {
    const int b = blockIdx.x;
    const int l = threadIdx.x;
    if (b < 384) {
        const float *Wa, *Wb; unsigned short *wh, *wl; int rel;
        if (b < 128) { Wa = W1sa; Wb = W1rw; wh = w1h;  wl = w1l;  rel = b; }
        else         { Wa = W2sa; Wb = W2rw; wh = wA2h; wl = wA2l; rel = b - 128; }
        const int ks  = rel >> 5;
        const int nfg = rel & 31;
        const float* W = (nfg < 16) ? Wa : Wb;
        const int col  = (nfg & 15) * 16 + (l & 15);
        const size_t base = ((size_t)rel * 64 + l) * 8;
        #pragma unroll
        for (int j = 0; j < 8; ++j) {
            const int k = ks * 32 + ((l >> 4) * 8) + j;
            unsigned short h, lw;
            bsplit(W[(size_t)k * Hd + col], h, lw);
            wh[base + j] = h;
            wl[base + j] = lw;
        }
    } else if (b < 640) {
        const int rel = b - 384;                  // [0,256)
        const int ks  = rel >> 5;
        const int nfg = rel & 31;
        const float* W = (nfg < 16) ? W2rc : W2sp;
        const int col  = (nfg & 15) * 16 + (l & 15);
        const size_t base = ((size_t)rel * 64 + l) * 8;
        #pragma unroll
        for (int j = 0; j < 8; ++j) {
            const int k = ks * 32 + ((l >> 4) * 8) + j;
            wP2h[base + j] = f2b(W[(size_t)k * Hd + col]);
        }
    } else if (b < 1152) {
        const int rel = b - 640;                  // [0,512)
        const int ks  = rel >> 5;
        const int nfg = rel & 31;
        const float* W = (nfg < 16) ? W1sp : W1rc;
        const int col  = (nfg & 15) * 16 + (l & 15);
        const size_t base = ((size_t)rel * 64 + l) * 8;
        #pragma unroll
        for (int j = 0; j < 8; ++j) {
            const int k = ks * 32 + ((l >> 4) * 8) + j;
            wP1h[base + j] = f2b(W[(size_t)k * Hd + col]);
        }
    } else {
        const int t     = (b - 1152) * 64 + l;    // 0..2047
        const int which = t >> 9;
        const int idx   = t & 511;
        const float* src; float* dst;
        if (which == 0)      { src = (idx < 256) ? b1sa : b1rw; dst = bc1;  }
        else if (which == 1) { src = (idx < 256) ? b2sa : b2rw; dst = bcA2; }
        else if (which == 2) { src = (idx < 256) ? b2rc : b2sp; dst = bcP2; }
        else                 { src = (idx < 256) ? b1sp : b1rc; dst = bcP1; }
        dst[idx] = src[idx & 255];
    }
}

// fp32 -> bf16 (truncation; exact for binary pf) streaming conversion
__global__ void conv_kernel(const float* __restrict__ in, unsigned short* __restrict__ out,
                            const long n4) {
    const long stride = (long)gridDim.x * blockDim.x;
    for (long i = (long)blockIdx.x * blockDim.x + threadIdx.x; i < n4; i += stride) {
        const float4 v = ((const float4*)in)[i];
        ((ushort4*)out)[i] = make_ushort4(
            (unsigned short)(__float_as_uint(v.x) >> 16),
            (unsigned short)(__float_as_uint(v.y) >> 16),
            (unsigned short)(__float_as_uint(v.z) >> 16),
            (unsigned short)(__float_as_uint(v.w) >> 16));
    }
}

// ---------------------------------------------------------------------------
// TILE2 MFMA GEMM (m97-style): 128x128 tile, BK=32, 4 waves (64x64 each,
// acc[4][4]). B ALWAYS staged via global_load_lds (fragment-packed table is
// contiguous 16B/lane). AMODE=1: bf16 A also via global_load_lds (per-lane
// pre-swizzled source, linear LDS dest). AMODE=0: fp32 A reg-staged +
// converted (R15 path). One barrier per K-step; staging for ks+1 issued
// before the MFMA burst of ks.
// ---------------------------------------------------------------------------
template<int AMODE>
__global__ void __launch_bounds__(256, 3)
mfma_tile2_kernel(const void* __restrict__ Av, const int KA, const int nks,
                  const unsigned short* __restrict__ wtab,
                  const float* __restrict__ bcat,
                  void* __restrict__ Oa, void* __restrict__ Ob,
                  const int bfA, const int bfB, const int Mtot) {
    extern __shared__ char smem[];                 // [2][ A:8KB | B:8KB ]
    const int tid = threadIdx.x;
    const int wid = tid >> 6;
    const int l   = tid & 63;
    const int c   = blockIdx.x & 3;
    const long m0 = (long)(blockIdx.x >> 2) * 128;
    const int wr  = wid >> 1, wc = wid & 1;

    // B global lane pointers: wave stages frags 2wid, 2wid+1 of this col-block
    const unsigned short* bg0 = wtab + ((size_t)(c * 8 + 2 * wid) * 512) + l * 8;
    const unsigned short* bg1 = bg0 + 512;

    // A pointers
    const unsigned short* ag0 = nullptr; const unsigned short* ag1 = nullptr;
    const float* Af = nullptr;
    long grow0 = 0, grow1 = 0; int kg = 0;
    if constexpr (AMODE == 1) {
        const unsigned short* A = (const unsigned short*)Av;
        long r0 = m0 + (2 * wid) * 16 + (l & 15);     if (r0 > Mtot - 1) r0 = Mtot - 1;
        long r1 = m0 + (2 * wid + 1) * 16 + (l & 15); if (r1 > Mtot - 1) r1 = Mtot - 1;
        ag0 = A + r0 * KA + ((l >> 4) * 8);
        ag1 = A + r1 * KA + ((l >> 4) * 8);
    } else {
        Af = (const float*)Av;
        const int f0 = tid >> 6;
        grow0 = m0 + f0 * 16 + (l & 15);       if (grow0 > Mtot - 1) grow0 = Mtot - 1;
        grow1 = m0 + (f0 + 4) * 16 + (l & 15); if (grow1 > Mtot - 1) grow1 = Mtot - 1;
        kg = (l >> 4) * 8;
    }

    float4 a00, a01, a10, a11;                     // AMODE=0 staging regs

#define STAGE_B(BUF, KS) { \
    char* Bb_ = smem + (BUF) * 16384 + 8192; \
    gld16(bg0 + (size_t)(KS) * 16384, Bb_ + wid * 2048); \
    gld16(bg1 + (size_t)(KS) * 16384, Bb_ + wid * 2048 + 1024); }
#define STAGE_A1(BUF, KS) { \
    char* Ab_ = smem + (BUF) * 16384; \
    gld16(ag0 + (KS) * 32, Ab_ + wid * 2048); \
    gld16(ag1 + (KS) * 32, Ab_ + wid * 2048 + 1024); }
#define LOAD_A0(KS) { \
    const float* p0_ = Af + grow0 * KA + (KS) * 32 + kg; \
    const float* p1_ = Af + grow1 * KA + (KS) * 32 + kg; \
    a00 = *(const float4*)p0_; a01 = *(const float4*)(p0_ + 4); \
    a10 = *(const float4*)p1_; a11 = *(const float4*)(p1_ + 4); }
#define WRITE_A0(BUF) { \
    char* Ab_ = smem + (BUF) * 16384; \
    *(uint4*)(Ab_ + tid * 16) = make_uint4(pk2(a00.x, a00.y), pk2(a00.z, a00.w), \
                                           pk2(a01.x, a01.y), pk2(a01.z, a01.w)); \
    *(uint4*)(Ab_ + (tid + 256) * 16) = make_uint4(pk2(a10.x, a10.y), pk2(a10.z, a10.w), \
                                                   pk2(a11.x, a11.y), pk2(a11.z, a11.w)); }

    // ---- accumulators, bias init ----
    f32x4 acc[4][4];
    #pragma unroll
    for (int nf = 0; nf < 4; ++nf) {
        const float b = bcat[c * 128 + wc * 64 + nf * 16 + (l & 15)];
        #pragma unroll
        for (int mf = 0; mf < 4; ++mf) acc[mf][nf] = (f32x4){b, b, b, b};
    }

    // ---- prologue ----
    STAGE_B(0, 0)
    if constexpr (AMODE == 1) { STAGE_A1(0, 0) }
    else { LOAD_A0(0) WRITE_A0(0) }
    __syncthreads();

    int cur = 0;
    for (int ks = 0; ks < nks; ++ks) {
        const bool more = (ks + 1 < nks);
        if (more) {
            STAGE_B(cur ^ 1, ks + 1)
            if constexpr (AMODE == 1) { STAGE_A1(cur ^ 1, ks + 1) }
            else { LOAD_A0(ks + 1) }
        }
        {
            const char* Ab = smem + cur * 16384;
            const char* Bb = Ab + 8192;
            bf16x8 af[4], bfv[4];
            #pragma unroll
            for (int mf = 0; mf < 4; ++mf)
                af[mf] = *(const bf16x8*)(Ab + ((wr * 4 + mf) * 64 + l) * 16);
            #pragma unroll
            for (int nf = 0; nf < 4; ++nf)
                bfv[nf] = *(const bf16x8*)(Bb + ((wc * 4 + nf) * 64 + l) * 16);
            #pragma unroll
            for (int nf = 0; nf < 4; ++nf) {
                #pragma unroll
                for (int mf = 0; mf < 4; ++mf)
                    acc[mf][nf] = __builtin_amdgcn_mfma_f32_16x16x32_bf16(af[mf], bfv[nf], acc[mf][nf], 0, 0, 0);
            }
        }
        if (more) { if constexpr (AMODE == 0) WRITE_A0(cur ^ 1) }
        __syncthreads();
        cur ^= 1;
    }
#undef STAGE_B
#undef STAGE_A1
#undef LOAD_A0
#undef WRITE_A0

    // ---- epilogue (guarded rows) ----
    #pragma unroll
    for (int mf = 0; mf < 4; ++mf) {
        #pragma unroll
        for (int nf = 0; nf < 4; ++nf) {
            const int gcol = c * 128 + wc * 64 + nf * 16 + (l & 15);
            void* O; int col, isbf;
            if (gcol < 256) { O = Oa; col = gcol;       isbf = bfA; }
            else            { O = Ob; col = gcol - 256; isbf = bfB; }
            const long row = m0 + wr * 64 + mf * 16 + ((l >> 4) * 4);
            const f32x4 v = acc[mf][nf];
            #pragma unroll
            for (int r = 0; r < 4; ++r) {
                if (row + r < Mtot) {
                    const float x = v[r];
                    if (isbf) ((unsigned short*)O)[(row + r) * Hd + col] = f2b(x);
                    else      ((float*)O)[(row + r) * Hd + col] = x;
                }
            }
        }
    }
}

// ---------------------------------------------------------------------------
// Dual-output MFMA GEMM (author GEMMs only): fp32 A, split-bf16 3-product.
// 32 rows/block. Proven R7 structure, unchanged.
// ---------------------------------------------------------------------------
__global__ void mfma_dual_kernel(const void* __restrict__ Av, const int K,
                                 const unsigned short* __restrict__ whi,
                                 const unsigned short* __restrict__ wlo,
                                 const float* __restrict__ bcat,
                                 void* __restrict__ Oa, void* __restrict__ Ob,
                                 const int actA, const int actB,
                                 const int bfA, const int bfB) {
    extern __shared__ char smem[];
    char* sh = smem;
    char* sl = smem + 32 * K * 2;
    const int  tid = threadIdx.x;
    const int  wid = tid >> 6;
    const int  l   = tid & 63;
    const long m0  = (long)blockIdx.x * 32;
    const int  rowStride = 2 * K;

    const int kq4 = K >> 2;
    const float* A = (const float*)Av;
    for (int i = tid; i < 32 * kq4; i += 256) {
        const int row = i / kq4;
        const int kq  = i - row * kq4;
        const float4 v = *(const float4*)(A + (m0 + row) * K + kq * 4);
        unsigned short h0, h1, h2, h3, l0, l1, l2, l3;
        bsplit(v.x, h0, l0); bsplit(v.y, h1, l1);
        bsplit(v.z, h2, l2); bsplit(v.w, h3, l3);
        const int ofs = row * rowStride + ((kq * 8) ^ ((row & 7) << 4));
        *(ushort4*)(sh + ofs) = make_ushort4(h0, h1, h2, h3);
        *(ushort4*)(sl + ofs) = make_ushort4(l0, l1, l2, l3);
    }
    __syncthreads();

    f32x4 acc[2][8];
    #pragma unroll
    for (int nf = 0; nf < 8; ++nf) {
        const float b = bcat[wid * 128 + nf * 16 + (l & 15)];
        acc[0][nf] = (f32x4){b, b, b, b};
        acc[1][nf] = (f32x4){b, b, b, b};
    }

    const int kb  = (l >> 4) * 16;
    const int r0  = l & 15;
    const int r1  = 16 + r0;
    const int sw  = (l & 7) << 4;
    const int ro0 = r0 * rowStride;
    const int ro1 = r1 * rowStride;
    for (int ks = 0; ks < (K >> 5); ++ks) {
        const int bk = (ks * 64 + kb) ^ sw;
        const bf16x8 ah0 = *(const bf16x8*)(sh + ro0 + bk);
        const bf16x8 ah1 = *(const bf16x8*)(sh + ro1 + bk);
        const bf16x8 al0 = *(const bf16x8*)(sl + ro0 + bk);
        const bf16x8 al1 = *(const bf16x8*)(sl + ro1 + bk);
        const size_t wbase = (((size_t)ks * 32 + wid * 8) * 64 + l) * 8;
        #pragma unroll
        for (int nf = 0; nf < 8; ++nf) {
            const bf16x8 bh = *(const bf16x8*)(whi + wbase + (size_t)nf * 512);
            const bf16x8 bl = *(const bf16x8*)(wlo + wbase + (size_t)nf * 512);
            acc[0][nf] = __builtin_amdgcn_mfma_f32_16x16x32_bf16(ah0, bh, acc[0][nf], 0, 0, 0);
            acc[1][nf] = __builtin_amdgcn_mfma_f32_16x16x32_bf16(ah1, bh, acc[1][nf], 0, 0, 0);
            acc[0][nf] = __builtin_amdgcn_mfma_f32_16x16x32_bf16(al0, bh, acc[0][nf], 0, 0, 0);
            acc[1][nf] = __builtin_amdgcn_mfma_f32_16x16x32_bf16(al1, bh, acc[1][nf], 0, 0, 0);
            acc[0][nf] = __builtin_amdgcn_mfma_f32_16x16x32_bf16(ah0, bl, acc[0][nf], 0, 0, 0);
            acc[1][nf] = __builtin_amdgcn_mfma_f32_16x16x32_bf16(ah1, bl, acc[1][nf], 0, 0, 0);
        }
    }

    #pragma unroll
    for (int mf = 0; mf < 2; ++mf) {
        #pragma unroll
        for (int nf = 0; nf < 8; ++nf) {
            const int colg = wid * 128 + nf * 16 + (l & 15);
            void* O;
            int col, act, isbf;
            if (colg < 256) { O = Oa; col = colg;       act = actA; isbf = bfA; }
            else            { O = Ob; col = colg - 256; act = actB; isbf = bfB; }
            const long row = m0 + mf * 16 + ((l >> 4) * 4);
            const f32x4 v = acc[mf][nf];
            #pragma unroll
            for (int r = 0; r < 4; ++r) {
                float x = v[r];
                if (act) x = x > 0.f ? x : expm1f(x);
                if (isbf) ((unsigned short*)O)[(row + r) * Hd + col] = f2b(x);
                else      ((float*)O)[(row + r) * Hd + col] = x;
            }
        }
    }
}

// ---------------------------------------------------------------------------
// Combined-relation CSR build. (proven)
// ---------------------------------------------------------------------------
__global__ void hist_kernel(const int* __restrict__ wdst, const int EW,
                            const int* __restrict__ cdst, const int EC,
                            int* __restrict__ cnt) {
    for (int i = blockIdx.x * blockDim.x + threadIdx.x; i < EW + EC; i += gridDim.x * blockDim.x) {
        const int d = (i < EW) ? wdst[i] : cdst[i - EW];
        atomicAdd(&cnt[d], 1);
    }
}

__global__ void scan1_kernel(int* __restrict__ data, const int n, int* __restrict__ bsum) {
    __shared__ int s[256];
    const int t = threadIdx.x;
    const int base = blockIdx.x * 1024 + t * 4;
    int v0 = (base + 0 < n) ? data[base + 0] : 0;
    int v1 = (base + 1 < n) ? data[base + 1] : 0;
    int v2 = (base + 2 < n) ? data[base + 2] : 0;
    int v3 = (base + 3 < n) ? data[base + 3] : 0;
    const int tsum = v0 + v1 + v2 + v3;
    s[t] = tsum;
    __syncthreads();
    for (int off = 1; off < 256; off <<= 1) {
        int y = (t >= off) ? s[t - off] : 0;
        __syncthreads();
        if (t >= off) s[t] += y;
        __syncthreads();
    }
    const int e = s[t] - tsum;
    if (base + 0 < n) data[base + 0] = e;
    if (base + 1 < n) data[base + 1] = e + v0;
    if (base + 2 < n) data[base + 2] = e + v0 + v1;
    if (base + 3 < n) data[base + 3] = e + v0 + v1 + v2;
    if (t == 255) bsum[blockIdx.x] = s[255];
}

__global__ void scan2_kernel(int* __restrict__ bsum, const int nb) {
    __shared__ int s[256];
    const int t = threadIdx.x;
    const int v = (t < nb) ? bsum[t] : 0;
    s[t] = v;
    __syncthreads();
    for (int off = 1; off < 256; off <<= 1) {
        int y = (t >= off) ? s[t - off] : 0;
        __syncthreads();
        if (t >= off) s[t] += y;
        __syncthreads();
    }
    if (t < nb) bsum[t] = s[t] - v;
}

__global__ void scan3_kernel(int* __restrict__ data, const int n, const int* __restrict__ bsum) {
    const int i = blockIdx.x * blockDim.x + threadIdx.x;
    if (i < n) data[i] += bsum[i >> 10];
}

__global__ void fill_kernel(const int* __restrict__ wsrc, const int* __restrict__ wdst,
                            const float* __restrict__ ww, const int EW,
                            const int* __restrict__ csrc, const int* __restrict__ cdst,
                            const float* __restrict__ cw, const int EC,
                            int* __restrict__ cur, int2* __restrict__ edges) {
    for (int i = blockIdx.x * blockDim.x + threadIdx.x; i < EW + EC; i += gridDim.x * blockDim.x) {
        int d, sp; float w;
        if (i < EW) { d = wdst[i]; sp = wsrc[i]; w = ww[i]; }
        else        { const int j = i - EW; d = cdst[j]; sp = N_A + csrc[j]; w = cw[j]; }
        const int p = atomicAdd(&cur[d], 1);
        edges[p] = make_int2(sp, __float_as_int(w));
    }
}

// ---------------------------------------------------------------------------
// Pull aggregation (R7-proven version). Unchanged.
// ---------------------------------------------------------------------------
struct AgChunk { ushort4 g0, g1, g2, g3; float w0, w1, w2, w3; };

__device__ __forceinline__ void ag_issue(const int2* __restrict__ eq, const int base, const int n,
                                         const unsigned short* __restrict__ msg,
                                         const int lane, AgChunk& C) {
#define AG_ONE(J, GG, WW) { \
    const int idx = base + (J); \
    const int2 ee = eq[min(idx, n - 1)]; \
    WW = (idx < n) ? __int_as_float(ee.y) : 0.f; \
    GG = ((const ushort4*)(msg + (size_t)ee.x * Hd))[lane]; }
    AG_ONE(0, C.g0, C.w0)
    AG_ONE(1, C.g1, C.w1)
    AG_ONE(2, C.g2, C.w2)
    AG_ONE(3, C.g3, C.w3)
#undef AG_ONE
}

__device__ __forceinline__ void ag_acc(const AgChunk& C, float4& acc) {
#define AG_A(GG, WW) { \
    acc.x = fmaf(WW, b2f(GG.x), acc.x); acc.y = fmaf(WW, b2f(GG.y), acc.y); \
    acc.z = fmaf(WW, b2f(GG.z), acc.z); acc.w = fmaf(WW, b2f(GG.w), acc.w); }
    AG_A(C.g0, C.w0) AG_A(C.g1, C.w1) AG_A(C.g2, C.w2) AG_A(C.g3, C.w3)
#undef AG_A
}

template<int IOBF>
__global__ void aggregate_kernel(void* __restrict__ iov,
                                 const unsigned short* __restrict__ msgAll,
                                 const int* __restrict__ off,
                                 const int2* __restrict__ edges,
                                 const int do_elu) {
    __shared__ int2 eq[1024];
    const int wid  = threadIdx.x >> 6;
    const int lane = threadIdx.x & 63;
    const int p0   = blockIdx.x * 4;
    const int sAll = (p0 == 0) ? 0 : off[p0 - 1];
    const int tot  = off[p0 + 3] - sAll;
    const bool fits = (tot <= 1024);
    if (fits)
        for (int i = threadIdx.x; i < tot; i += 256) eq[i] = edges[sAll + i];
    __syncthreads();

    const int p = p0 + wid;
    const int s = (p == 0) ? 0 : off[p - 1];
    const int e = off[p];
    const int n = e - s;

    float4 acc;
    if constexpr (IOBF) {
        const ushort4 t = ((const ushort4*)((const unsigned short*)iov + (size_t)p * Hd))[lane];
        acc = make_float4(b2f(t.x), b2f(t.y), b2f(t.z), b2f(t.w));
    } else {
        acc = ((const float4*)((const float*)iov + (size_t)p * Hd))[lane];
    }

    if (n > 0) {
        if (fits) {
            const int2* eqw = eq + (s - sAll);
            int nc = (n + 3) >> 2;
            nc += (nc & 1);
            AgChunk CA, CB;
            ag_issue(eqw, 0, n, msgAll, lane, CA);
            int c = 1;
            for (; c + 1 < nc; c += 2) {
                ag_issue(eqw, 4 * c, n, msgAll, lane, CB);
                ag_acc(CA, acc);
                ag_issue(eqw, 4 * (c + 1), n, msgAll, lane, CA);
                ag_acc(CB, acc);
            }
            ag_issue(eqw, 4 * (nc - 1), n, msgAll, lane, CB);
            ag_acc(CA, acc);
            ag_acc(CB, acc);
        } else {
            for (int i = s; i < e; ++i) {
                const int2 ee = edges[i];
                const ushort4 g = ((const ushort4*)(msgAll + (size_t)ee.x * Hd))[lane];
                const float w = __int_as_float(ee.y);
                acc.x = fmaf(w, b2f(g.x), acc.x); acc.y = fmaf(w, b2f(g.y), acc.y);
                acc.z = fmaf(w, b2f(g.z), acc.z); acc.w = fmaf(w, b2f(g.w), acc.w);
            }
        }
    }
    if (do_elu) {
        acc.x = acc.x > 0.f ? acc.x : expm1f(acc.x);
        acc.y = acc.y > 0.f ? acc.y : expm1f(acc.y);
        acc.z = acc.z > 0.f ? acc.z : expm1f(acc.z);
        acc.w = acc.w > 0.f ? acc.w : expm1f(acc.w);
    }
    if constexpr (IOBF) {
        ((ushort4*)((unsigned short*)iov + (size_t)p * Hd))[lane] =
            make_ushort4(f2b(acc.x), f2b(acc.y), f2b(acc.z), f2b(acc.w));
    } else {
        ((float4*)((float*)iov + (size_t)p * Hd))[lane] = acc;
    }
}

extern "C" void kernel_launch(void* const* d_in, const int* in_sizes, int n_in,
                              void* d_out, int out_size, void* d_ws, size_t ws_size,
                              hipStream_t stream) {
    const float* pf    = (const float*)d_in[0];
    const float* ae    = (const float*)d_in[1];
    const int*   wsrc  = (const int*)d_in[2];
    const int*   wdst  = (const int*)d_in[3];
    const float* ww    = (const float*)d_in[4];
    const int*   csrc  = (const int*)d_in[5];
    const int*   cdst  = (const int*)d_in[6];
    const float* cw    = (const float*)d_in[7];
    const float* W1sp  = (const float*)d_in[8];
    const float* b1sp  = (const float*)d_in[9];
    const float* W1sa  = (const float*)d_in[10];
    const float* b1sa  = (const float*)d_in[11];
    const float* W1rw  = (const float*)d_in[12];
    const float* b1rw  = (const float*)d_in[13];
    const float* W1rc  = (const float*)d_in[14];
    const float* b1rc  = (const float*)d_in[15];
    const float* W2sp  = (const float*)d_in[16];
    const float* b2sp  = (const float*)d_in[17];
    const float* W2sa  = (const float*)d_in[18];
    const float* b2sa  = (const float*)d_in[19];
    const float* W2rw  = (const float*)d_in[20];
    const float* b2rw  = (const float*)d_in[21];
    const float* W2rc  = (const float*)d_in[22];
    const float* b2rc  = (const float*)d_in[23];

    const int E_W = in_sizes[2];
    const int E_C = in_sizes[5];

    float* outP = (float*)d_out;                        // [N_P, 256] fp32
    float* outA = outP + (size_t)N_P * Hd;              // [N_A, 256] fp32

    // Workspace layout (as R15) + optional pfb at the end:
    float*          xa1    = (float*)d_ws;
    unsigned short* xp1b   = (unsigned short*)(xa1 + (size_t)N_A * Hd);
    unsigned short* msgAll = xp1b + (size_t)N_P * Hd;
    unsigned short* msgP   = msgAll + (size_t)N_A * Hd;
    int*            off    = (int*)(msgAll + (size_t)(N_A + N_P) * Hd);
    int2*           edges  = (int2*)(off + N_P);
    int*            bsum   = (int*)(edges + (E_W + E_C));
    float*          bc1    = (float*)(bsum + 256);
    float*          bcA2   = bc1 + 512;
    float*          bcP2   = bcA2 + 512;
    float*          bcP1   = bcP2 + 512;
    unsigned short* w1h    = (unsigned short*)(bcP1 + 512);
    unsigned short* w1l    = w1h  + (size_t)128 * 512;
    unsigned short* wA2h   = w1l  + (size_t)128 * 512;
    unsigned short* wA2l   = wA2h + (size_t)256 * 512;
    unsigned short* wP2h   = wA2l + (size_t)256 * 512;   // 256*512 shorts
    unsigned short* wP1h   = wP2h + (size_t)256 * 512;   // 512*512 shorts
    unsigned short* pfb    = (unsigned short*)
        (((uintptr_t)(wP1h + (size_t)512 * 512) + 63) & ~(uintptr_t)63);
    const size_t need = ((char*)(pfb + (size_t)N_P * F_P)) - (char*)d_ws;
    const bool usePfb = (ws_size >= need);

    const dim3 blk(256);
    const int  nb  = (N_P + 1023) / 1024;     // 98
    const int  gM  = (N_P + 127) / 128;       // 782
    const int  gP  = gM * 4;                  // 4 col-blocks of 128

    // ---------------- prep ----------------
    prep_kernel<<<1184, 64, 0, stream>>>(W1sa, W1rw, W2sa, W2rw, W2rc, W2sp, W1sp, W1rc,
                                         b1sa, b1rw, b2sa, b2rw, b2rc, b2sp, b1sp, b1rc,
                                         w1h, w1l, wA2h, wA2l, wP2h, wP1h,
                                         bc1, bcA2, bcP2, bcP1);

    // ---------------- combined CSR ----------------
    hipMemsetAsync(off, 0, (size_t)N_P * sizeof(int), stream);
    hist_kernel<<<1024, blk, 0, stream>>>(wdst, E_W, cdst, E_C, off);
    scan1_kernel<<<nb, blk, 0, stream>>>(off, N_P, bsum);
    scan2_kernel<<<1,  blk, 0, stream>>>(bsum, nb);
    scan3_kernel<<<(N_P + 255) / 256, blk, 0, stream>>>(off, N_P, bsum);
    fill_kernel<<<1024, blk, 0, stream>>>(wsrc, wdst, ww, E_W, csrc, cdst, cw, E_C,
                                          off, edges);

    // ---------------- Layer 1 ----------------
    if (usePfb) {
        conv_kernel<<<2048, blk, 0, stream>>>(pf, pfb, (long)N_P * F_P / 4);
        mfma_tile2_kernel<1><<<gP, blk, 32768, stream>>>(pfb, 512, 16, wP1h, bcP1,
                                                         xp1b, msgP, 1, 1, N_P);
    } else {
        mfma_tile2_kernel<0><<<gP, blk, 32768, stream>>>(pf, 512, 16, wP1h, bcP1,
                                                         xp1b, msgP, 1, 1, N_P);
    }
    // author self (ELU, fp32 xa1) + writes msg (bf16 into msgAll)
    mfma_dual_kernel<<<N_A / 32, blk, 32 * 128 * 4, stream>>>(ae, 128, w1h, w1l, bc1,
                                                              xa1, msgAll, 1, 0, 0, 1);
    aggregate_kernel<1><<<N_P / 4, blk, 0, stream>>>(xp1b, msgAll, off, edges, 1);

    // ---------------- Layer 2 ----------------
    mfma_dual_kernel<<<N_A / 32, blk, 32 * 256 * 4, stream>>>(xa1, 256, wA2h, wA2l, bcA2,
                                                              outA, msgAll, 0, 0, 0, 1);
    // paper: A = xp1b (bf16, gld), B = RNE-bf16 (W2rc|W2sp) K=256, 1-product
    mfma_tile2_kernel<1><<<gP, blk, 32768, stream>>>(xp1b, 256, 8, wP2h, bcP2,
                                                     msgP, outP, 1, 0, N_P);
    aggregate_kernel<0><<<N_P / 4, blk, 0, stream>>>(outP, msgAll, off, edges, 0);
}

// Round 17
// 453.783 us; speedup vs baseline: 1.3846x; 1.0495x over previous
//
#include <hip/hip_runtime.h>
#include <cstdint>
#include <cstddef>

constexpr int Hd  = 256;
constexpr int N_P = 100000;
constexpr int N_A = 20000;
constexpr int F_P = 512;
constexpr int D_A = 128;

typedef short bf16x8 __attribute__((ext_vector_type(8)));
typedef float f32x4  __attribute__((ext_vector_type(4)));

__device__ __forceinline__ unsigned short f2b(float x) {
    unsigned u = __float_as_uint(x);
    u += 0x7fffu + ((u >> 16) & 1u);
    return (unsigned short)(u >> 16);
}
__device__ __forceinline__ float b2f(unsigned short h) {
    return __uint_as_float((unsigned)h << 16);
}
__device__ __forceinline__ unsigned pk2(float lo, float hi) {
    return (__float_as_uint(lo) >> 16) | (__float_as_uint(hi) & 0xffff0000u);
}
__device__ __forceinline__ void bsplit(float x, unsigned short& hi, unsigned short& lo) {
    const unsigned u = __float_as_uint(x);
    hi = (unsigned short)(u >> 16);
    const float r = x - __uint_as_float(u & 0xffff0000u);
    lo = (unsigned short)(__float_as_uint(r) >> 16);
}

// async global->LDS, 16B per lane (m173 pre-swizzled-source pattern).
__device__ __forceinline__ void gld16(const void* g, void* l) {
    __builtin_amdgcn_global_load_lds(
        (const __attribute__((address_space(1))) unsigned int*)g,
        (__attribute__((address_space(3))) unsigned int*)l, 16, 0, 0);
}

// ---------------------------------------------------------------------------
// prep: pack W tables into MFMA B-fragment layout + bias concats. (proven)
// ---------------------------------------------------------------------------
__global__ void prep_kernel(const float* __restrict__ W1sa, const float* __restrict__ W1rw,
                            const float* __restrict__ W2sa, const float* __restrict__ W2rw,
                            const float* __restrict__ W2rc, const float* __restrict__ W2sp,
                            const float* __restrict__ W1sp, const float* __restrict__ W1rc,
                            const float* __restrict__ b1sa, const float* __restrict__ b1rw,
                            const float* __restrict__ b2sa, const float* __restrict__ b2rw,
                            const float* __restrict__ b2rc, const float* __restrict__ b2sp,
                            const float* __restrict__ b1sp, const float* __restrict__ b1rc,
                            unsigned short* __restrict__ w1h,  unsigned short* __restrict__ w1l,
                            unsigned short* __restrict__ wA2h, unsigned short* __restrict__ wA2l,
                            unsigned short* __restrict__ wP2h,
                            unsigned short* __restrict__ wP1h,
                            float* __restrict__ bc1, float* __restrict__ bcA2,
                            float* __restrict__ bcP2, float* __restrict__ bcP1) {
    const int b = blockIdx.x;
    const int l = threadIdx.x;
    if (b < 384) {
        const float *Wa, *Wb; unsigned short *wh, *wl; int rel;
        if (b < 128) { Wa = W1sa; Wb = W1rw; wh = w1h;  wl = w1l;  rel = b; }
        else         { Wa = W2sa; Wb = W2rw; wh = wA2h; wl = wA2l; rel = b - 128; }
        const int ks  = rel >> 5;
        const int nfg = rel & 31;
        const float* W = (nfg < 16) ? Wa : Wb;
        const int col  = (nfg & 15) * 16 + (l & 15);
        const size_t base = ((size_t)rel * 64 + l) * 8;
        #pragma unroll
        for (int j = 0; j < 8; ++j) {
            const int k = ks * 32 + ((l >> 4) * 8) + j;
            unsigned short h, lw;
            bsplit(W[(size_t)k * Hd + col], h, lw);
            wh[base + j] = h;
            wl[base + j] = lw;
        }
    } else if (b < 640) {
        const int rel = b - 384;                  // [0,256)
        const int ks  = rel >> 5;
        const int nfg = rel & 31;
        const float* W = (nfg < 16) ? W2rc : W2sp;
        const int col  = (nfg & 15) * 16 + (l & 15);
        const size_t base = ((size_t)rel * 64 + l) * 8;
        #pragma unroll
        for (int j = 0; j < 8; ++j) {
            const int k = ks * 32 + ((l >> 4) * 8) + j;
            wP2h[base + j] = f2b(W[(size_t)k * Hd + col]);
        }
    } else if (b < 1152) {
        const int rel = b - 640;                  // [0,512)
        const int ks  = rel >> 5;
        const int nfg = rel & 31;
        const float* W = (nfg < 16) ? W1sp : W1rc;
        const int col  = (nfg & 15) * 16 + (l & 15);
        const size_t base = ((size_t)rel * 64 + l) * 8;
        #pragma unroll
        for (int j = 0; j < 8; ++j) {
            const int k = ks * 32 + ((l >> 4) * 8) + j;
            wP1h[base + j] = f2b(W[(size_t)k * Hd + col]);
        }
    } else {
        const int t     = (b - 1152) * 64 + l;    // 0..2047
        const int which = t >> 9;
        const int idx   = t & 511;
        const float* src; float* dst;
        if (which == 0)      { src = (idx < 256) ? b1sa : b1rw; dst = bc1;  }
        else if (which == 1) { src = (idx < 256) ? b2sa : b2rw; dst = bcA2; }
        else if (which == 2) { src = (idx < 256) ? b2rc : b2sp; dst = bcP2; }
        else                 { src = (idx < 256) ? b1sp : b1rc; dst = bcP1; }
        dst[idx] = src[idx & 255];
    }
}

// fp32 -> bf16 (truncation; exact for binary pf) streaming conversion
__global__ void conv_kernel(const float* __restrict__ in, unsigned short* __restrict__ out,
                            const long n4) {
    const long stride = (long)gridDim.x * blockDim.x;
    for (long i = (long)blockIdx.x * blockDim.x + threadIdx.x; i < n4; i += stride) {
        const float4 v = ((const float4*)in)[i];
        ((ushort4*)out)[i] = make_ushort4(
            (unsigned short)(__float_as_uint(v.x) >> 16),
            (unsigned short)(__float_as_uint(v.y) >> 16),
            (unsigned short)(__float_as_uint(v.z) >> 16),
            (unsigned short)(__float_as_uint(v.w) >> 16));
    }
}

// ---------------------------------------------------------------------------
// TILE2 MFMA GEMM (m97-style): 128x128 tile, BK=32, 4 waves (64x64 each,
// acc[4][4]). B via global_load_lds; AMODE=1: bf16 A via global_load_lds;
// AMODE=0: fp32 A reg-staged (fallback). One barrier per K-step.
// XCD-grouped block mapping: hw block d -> x=d&7, c=(d>>3)&3, r=(d>>5)*8+x,
// so the 4 col-blocks sharing an A row-panel land on the same XCD L2
// (bijective on padded domain; blocks with r>=gM return before any barrier).
// ---------------------------------------------------------------------------
template<int AMODE>
__global__ void __launch_bounds__(256, 3)
mfma_tile2_kernel(const void* __restrict__ Av, const int KA, const int nks,
                  const unsigned short* __restrict__ wtab,
                  const float* __restrict__ bcat,
                  void* __restrict__ Oa, void* __restrict__ Ob,
                  const int bfA, const int bfB, const int Mtot, const int gM) {
    const int d = blockIdx.x;
    const int r = ((d >> 5) << 3) + (d & 7);
    if (r >= gM) return;
    const int c = (d >> 3) & 3;

    extern __shared__ char smem[];                 // [2][ A:8KB | B:8KB ]
    const int tid = threadIdx.x;
    const int wid = tid >> 6;
    const int l   = tid & 63;
    const long m0 = (long)r * 128;
    const int wr  = wid >> 1, wc = wid & 1;

    const unsigned short* bg0 = wtab + ((size_t)(c * 8 + 2 * wid) * 512) + l * 8;
    const unsigned short* bg1 = bg0 + 512;

    const unsigned short* ag0 = nullptr; const unsigned short* ag1 = nullptr;
    const float* Af = nullptr;
    long grow0 = 0, grow1 = 0; int kg = 0;
    if constexpr (AMODE == 1) {
        const unsigned short* A = (const unsigned short*)Av;
        long r0 = m0 + (2 * wid) * 16 + (l & 15);     if (r0 > Mtot - 1) r0 = Mtot - 1;
        long r1 = m0 + (2 * wid + 1) * 16 + (l & 15); if (r1 > Mtot - 1) r1 = Mtot - 1;
        ag0 = A + r0 * KA + ((l >> 4) * 8);
        ag1 = A + r1 * KA + ((l >> 4) * 8);
    } else {
        Af = (const float*)Av;
        const int f0 = tid >> 6;
        grow0 = m0 + f0 * 16 + (l & 15);       if (grow0 > Mtot - 1) grow0 = Mtot - 1;
        grow1 = m0 + (f0 + 4) * 16 + (l & 15); if (grow1 > Mtot - 1) grow1 = Mtot - 1;
        kg = (l >> 4) * 8;
    }

    float4 a00, a01, a10, a11;

#define STAGE_B(BUF, KS) { \
    char* Bb_ = smem + (BUF) * 16384 + 8192; \
    gld16(bg0 + (size_t)(KS) * 16384, Bb_ + wid * 2048); \
    gld16(bg1 + (size_t)(KS) * 16384, Bb_ + wid * 2048 + 1024); }
#define STAGE_A1(BUF, KS) { \
    char* Ab_ = smem + (BUF) * 16384; \
    gld16(ag0 + (KS) * 32, Ab_ + wid * 2048); \
    gld16(ag1 + (KS) * 32, Ab_ + wid * 2048 + 1024); }
#define LOAD_A0(KS) { \
    const float* p0_ = Af + grow0 * KA + (KS) * 32 + kg; \
    const float* p1_ = Af + grow1 * KA + (KS) * 32 + kg; \
    a00 = *(const float4*)p0_; a01 = *(const float4*)(p0_ + 4); \
    a10 = *(const float4*)p1_; a11 = *(const float4*)(p1_ + 4); }
#define WRITE_A0(BUF) { \
    char* Ab_ = smem + (BUF) * 16384; \
    *(uint4*)(Ab_ + tid * 16) = make_uint4(pk2(a00.x, a00.y), pk2(a00.z, a00.w), \
                                           pk2(a01.x, a01.y), pk2(a01.z, a01.w)); \
    *(uint4*)(Ab_ + (tid + 256) * 16) = make_uint4(pk2(a10.x, a10.y), pk2(a10.z, a10.w), \
                                                   pk2(a11.x, a11.y), pk2(a11.z, a11.w)); }

    f32x4 acc[4][4];
    #pragma unroll
    for (int nf = 0; nf < 4; ++nf) {
        const float b = bcat[c * 128 + wc * 64 + nf * 16 + (l & 15)];
        #pragma unroll
        for (int mf = 0; mf < 4; ++mf) acc[mf][nf] = (f32x4){b, b, b, b};
    }

    STAGE_B(0, 0)
    if constexpr (AMODE == 1) { STAGE_A1(0, 0) }
    else { LOAD_A0(0) WRITE_A0(0) }
    __syncthreads();

    int cur = 0;
    for (int ks = 0; ks < nks; ++ks) {
        const bool more = (ks + 1 < nks);
        if (more) {
            STAGE_B(cur ^ 1, ks + 1)
            if constexpr (AMODE == 1) { STAGE_A1(cur ^ 1, ks + 1) }
            else { LOAD_A0(ks + 1) }
        }
        {
            const char* Ab = smem + cur * 16384;
            const char* Bb = Ab + 8192;
            bf16x8 af[4], bfv[4];
            #pragma unroll
            for (int mf = 0; mf < 4; ++mf)
                af[mf] = *(const bf16x8*)(Ab + ((wr * 4 + mf) * 64 + l) * 16);
            #pragma unroll
            for (int nf = 0; nf < 4; ++nf)
                bfv[nf] = *(const bf16x8*)(Bb + ((wc * 4 + nf) * 64 + l) * 16);
            #pragma unroll
            for (int nf = 0; nf < 4; ++nf) {
                #pragma unroll
                for (int mf = 0; mf < 4; ++mf)
                    acc[mf][nf] = __builtin_amdgcn_mfma_f32_16x16x32_bf16(af[mf], bfv[nf], acc[mf][nf], 0, 0, 0);
            }
        }
        if (more) { if constexpr (AMODE == 0) WRITE_A0(cur ^ 1) }
        __syncthreads();
        cur ^= 1;
    }
#undef STAGE_B
#undef STAGE_A1
#undef LOAD_A0
#undef WRITE_A0

    #pragma unroll
    for (int mf = 0; mf < 4; ++mf) {
        #pragma unroll
        for (int nf = 0; nf < 4; ++nf) {
            const int gcol = c * 128 + wc * 64 + nf * 16 + (l & 15);
            void* O; int col, isbf;
            if (gcol < 256) { O = Oa; col = gcol;       isbf = bfA; }
            else            { O = Ob; col = gcol - 256; isbf = bfB; }
            const long row = m0 + wr * 64 + mf * 16 + ((l >> 4) * 4);
            const f32x4 v = acc[mf][nf];
            #pragma unroll
            for (int rr = 0; rr < 4; ++rr) {
                if (row + rr < Mtot) {
                    const float x = v[rr];
                    if (isbf) ((unsigned short*)O)[(row + rr) * Hd + col] = f2b(x);
                    else      ((float*)O)[(row + rr) * Hd + col] = x;
                }
            }
        }
    }
}

// ---------------------------------------------------------------------------
// Dual-output MFMA GEMM (author GEMMs only): fp32 A, split-bf16 3-product.
// ---------------------------------------------------------------------------
__global__ void mfma_dual_kernel(const void* __restrict__ Av, const int K,
                                 const unsigned short* __restrict__ whi,
                                 const unsigned short* __restrict__ wlo,
                                 const float* __restrict__ bcat,
                                 void* __restrict__ Oa, void* __restrict__ Ob,
                                 const int actA, const int actB,
                                 const int bfA, const int bfB) {
    extern __shared__ char smem[];
    char* sh = smem;
    char* sl = smem + 32 * K * 2;
    const int  tid = threadIdx.x;
    const int  wid = tid >> 6;
    const int  l   = tid & 63;
    const long m0  = (long)blockIdx.x * 32;
    const int  rowStride = 2 * K;

    const int kq4 = K >> 2;
    const float* A = (const float*)Av;
    for (int i = tid; i < 32 * kq4; i += 256) {
        const int row = i / kq4;
        const int kq  = i - row * kq4;
        const float4 v = *(const float4*)(A + (m0 + row) * K + kq * 4);
        unsigned short h0, h1, h2, h3, l0, l1, l2, l3;
        bsplit(v.x, h0, l0); bsplit(v.y, h1, l1);
        bsplit(v.z, h2, l2); bsplit(v.w, h3, l3);
        const int ofs = row * rowStride + ((kq * 8) ^ ((row & 7) << 4));
        *(ushort4*)(sh + ofs) = make_ushort4(h0, h1, h2, h3);
        *(ushort4*)(sl + ofs) = make_ushort4(l0, l1, l2, l3);
    }
    __syncthreads();

    f32x4 acc[2][8];
    #pragma unroll
    for (int nf = 0; nf < 8; ++nf) {
        const float b = bcat[wid * 128 + nf * 16 + (l & 15)];
        acc[0][nf] = (f32x4){b, b, b, b};
        acc[1][nf] = (f32x4){b, b, b, b};
    }

    const int kb  = (l >> 4) * 16;
    const int r0  = l & 15;
    const int r1  = 16 + r0;
    const int sw  = (l & 7) << 4;
    const int ro0 = r0 * rowStride;
    const int ro1 = r1 * rowStride;
    for (int ks = 0; ks < (K >> 5); ++ks) {
        const int bk = (ks * 64 + kb) ^ sw;
        const bf16x8 ah0 = *(const bf16x8*)(sh + ro0 + bk);
        const bf16x8 ah1 = *(const bf16x8*)(sh + ro1 + bk);
        const bf16x8 al0 = *(const bf16x8*)(sl + ro0 + bk);
        const bf16x8 al1 = *(const bf16x8*)(sl + ro1 + bk);
        const size_t wbase = (((size_t)ks * 32 + wid * 8) * 64 + l) * 8;
        #pragma unroll
        for (int nf = 0; nf < 8; ++nf) {
            const bf16x8 bh = *(const bf16x8*)(whi + wbase + (size_t)nf * 512);
            const bf16x8 bl = *(const bf16x8*)(wlo + wbase + (size_t)nf * 512);
            acc[0][nf] = __builtin_amdgcn_mfma_f32_16x16x32_bf16(ah0, bh, acc[0][nf], 0, 0, 0);
            acc[1][nf] = __builtin_amdgcn_mfma_f32_16x16x32_bf16(ah1, bh, acc[1][nf], 0, 0, 0);
            acc[0][nf] = __builtin_amdgcn_mfma_f32_16x16x32_bf16(al0, bh, acc[0][nf], 0, 0, 0);
            acc[1][nf] = __builtin_amdgcn_mfma_f32_16x16x32_bf16(al1, bh, acc[1][nf], 0, 0, 0);
            acc[0][nf] = __builtin_amdgcn_mfma_f32_16x16x32_bf16(ah0, bl, acc[0][nf], 0, 0, 0);
            acc[1][nf] = __builtin_amdgcn_mfma_f32_16x16x32_bf16(ah1, bl, acc[1][nf], 0, 0, 0);
        }
    }

    #pragma unroll
    for (int mf = 0; mf < 2; ++mf) {
        #pragma unroll
        for (int nf = 0; nf < 8; ++nf) {
            const int colg = wid * 128 + nf * 16 + (l & 15);
            void* O;
            int col, act, isbf;
            if (colg < 256) { O = Oa; col = colg;       act = actA; isbf = bfA; }
            else            { O = Ob; col = colg - 256; act = actB; isbf = bfB; }
            const long row = m0 + mf * 16 + ((l >> 4) * 4);
            const f32x4 v = acc[mf][nf];
            #pragma unroll
            for (int r = 0; r < 4; ++r) {
                float x = v[r];
                if (act) x = x > 0.f ? x : expm1f(x);
                if (isbf) ((unsigned short*)O)[(row + r) * Hd + col] = f2b(x);
                else      ((float*)O)[(row + r) * Hd + col] = x;
            }
        }
    }
}

// ---------------------------------------------------------------------------
// Combined-relation CSR build. (proven)
// ---------------------------------------------------------------------------
__global__ void hist_kernel(const int* __restrict__ wdst, const int EW,
                            const int* __restrict__ cdst, const int EC,
                            int* __restrict__ cnt) {
    for (int i = blockIdx.x * blockDim.x + threadIdx.x; i < EW + EC; i += gridDim.x * blockDim.x) {
        const int d = (i < EW) ? wdst[i] : cdst[i - EW];
        atomicAdd(&cnt[d], 1);
    }
}

__global__ void scan1_kernel(int* __restrict__ data, const int n, int* __restrict__ bsum) {
    __shared__ int s[256];
    const int t = threadIdx.x;
    const int base = blockIdx.x * 1024 + t * 4;
    int v0 = (base + 0 < n) ? data[base + 0] : 0;
    int v1 = (base + 1 < n) ? data[base + 1] : 0;
    int v2 = (base + 2 < n) ? data[base + 2] : 0;
    int v3 = (base + 3 < n) ? data[base + 3] : 0;
    const int tsum = v0 + v1 + v2 + v3;
    s[t] = tsum;
    __syncthreads();
    for (int off = 1; off < 256; off <<= 1) {
        int y = (t >= off) ? s[t - off] : 0;
        __syncthreads();
        if (t >= off) s[t] += y;
        __syncthreads();
    }
    const int e = s[t] - tsum;
    if (base + 0 < n) data[base + 0] = e;
    if (base + 1 < n) data[base + 1] = e + v0;
    if (base + 2 < n) data[base + 2] = e + v0 + v1;
    if (base + 3 < n) data[base + 3] = e + v0 + v1 + v2;
    if (t == 255) bsum[blockIdx.x] = s[255];
}

__global__ void scan2_kernel(int* __restrict__ bsum, const int nb) {
    __shared__ int s[256];
    const int t = threadIdx.x;
    const int v = (t < nb) ? bsum[t] : 0;
    s[t] = v;
    __syncthreads();
    for (int off = 1; off < 256; off <<= 1) {
        int y = (t >= off) ? s[t - off] : 0;
        __syncthreads();
        if (t >= off) s[t] += y;
        __syncthreads();
    }
    if (t < nb) bsum[t] = s[t] - v;
}

__global__ void scan3_kernel(int* __restrict__ data, const int n, const int* __restrict__ bsum) {
    const int i = blockIdx.x * blockDim.x + threadIdx.x;
    if (i < n) data[i] += bsum[i >> 10];
}

__global__ void fill_kernel(const int* __restrict__ wsrc, const int* __restrict__ wdst,
                            const float* __restrict__ ww, const int EW,
                            const int* __restrict__ csrc, const int* __restrict__ cdst,
                            const float* __restrict__ cw, const int EC,
                            int* __restrict__ cur, int2* __restrict__ edges) {
    for (int i = blockIdx.x * blockDim.x + threadIdx.x; i < EW + EC; i += gridDim.x * blockDim.x) {
        int d, sp; float w;
        if (i < EW) { d = wdst[i]; sp = wsrc[i]; w = ww[i]; }
        else        { const int j = i - EW; d = cdst[j]; sp = N_A + csrc[j]; w = cw[j]; }
        const int p = atomicAdd(&cur[d], 1);
        edges[p] = make_int2(sp, __float_as_int(w));
    }
}

// ---------------------------------------------------------------------------
// Pull aggregation (R7-proven structure).
// MODE 0: fp32 in-place. MODE 1: bf16 in-place (+ELU flag). MODE 2: read
// bf16 self from iov, write fp32 to outv (separate buffers).
// ---------------------------------------------------------------------------
struct AgChunk { ushort4 g0, g1, g2, g3; float w0, w1, w2, w3; };

__device__ __forceinline__ void ag_issue(const int2* __restrict__ eq, const int base, const int n,
                                         const unsigned short* __restrict__ msg,
                                         const int lane, AgChunk& C) {
#define AG_ONE(J, GG, WW) { \
    const int idx = base + (J); \
    const int2 ee = eq[min(idx, n - 1)]; \
    WW = (idx < n) ? __int_as_float(ee.y) : 0.f; \
    GG = ((const ushort4*)(msg + (size_t)ee.x * Hd))[lane]; }
    AG_ONE(0, C.g0, C.w0)
    AG_ONE(1, C.g1, C.w1)
    AG_ONE(2, C.g2, C.w2)
    AG_ONE(3, C.g3, C.w3)
#undef AG_ONE
}

__device__ __forceinline__ void ag_acc(const AgChunk& C, float4& acc) {
#define AG_A(GG, WW) { \
    acc.x = fmaf(WW, b2f(GG.x), acc.x); acc.y = fmaf(WW, b2f(GG.y), acc.y); \
    acc.z = fmaf(WW, b2f(GG.z), acc.z); acc.w = fmaf(WW, b2f(GG.w), acc.w); }
    AG_A(C.g0, C.w0) AG_A(C.g1, C.w1) AG_A(C.g2, C.w2) AG_A(C.g3, C.w3)
#undef AG_A
}

template<int MODE>
__global__ void aggregate_kernel(void* __restrict__ iov, void* __restrict__ outv,
                                 const unsigned short* __restrict__ msgAll,
                                 const int* __restrict__ off,
                                 const int2* __restrict__ edges,
                                 const int do_elu) {
    __shared__ int2 eq[1024];
    const int wid  = threadIdx.x >> 6;
    const int lane = threadIdx.x & 63;
    const int p0   = blockIdx.x * 4;
    const int sAll = (p0 == 0) ? 0 : off[p0 - 1];
    const int tot  = off[p0 + 3] - sAll;
    const bool fits = (tot <= 1024);
    if (fits)
        for (int i = threadIdx.x; i < tot; i += 256) eq[i] = edges[sAll + i];
    __syncthreads();

    const int p = p0 + wid;
    const int s = (p == 0) ? 0 : off[p - 1];
    const int e = off[p];
    const int n = e - s;

    float4 acc;
    if constexpr (MODE >= 1) {
        const ushort4 t = ((const ushort4*)((const unsigned short*)iov + (size_t)p * Hd))[lane];
        acc = make_float4(b2f(t.x), b2f(t.y), b2f(t.z), b2f(t.w));
    } else {
        acc = ((const float4*)((const float*)iov + (size_t)p * Hd))[lane];
    }

    if (n > 0) {
        if (fits) {
            const int2* eqw = eq + (s - sAll);
            int nc = (n + 3) >> 2;
            nc += (nc & 1);
            AgChunk CA, CB;
            ag_issue(eqw, 0, n, msgAll, lane, CA);
            int c = 1;
            for (; c + 1 < nc; c += 2) {
                ag_issue(eqw, 4 * c, n, msgAll, lane, CB);
                ag_acc(CA, acc);
                ag_issue(eqw, 4 * (c + 1), n, msgAll, lane, CA);
                ag_acc(CB, acc);
            }
            ag_issue(eqw, 4 * (nc - 1), n, msgAll, lane, CB);
            ag_acc(CA, acc);
            ag_acc(CB, acc);
        } else {
            for (int i = s; i < e; ++i) {
                const int2 ee = edges[i];
                const ushort4 g = ((const ushort4*)(msgAll + (size_t)ee.x * Hd))[lane];
                const float w = __int_as_float(ee.y);
                acc.x = fmaf(w, b2f(g.x), acc.x); acc.y = fmaf(w, b2f(g.y), acc.y);
                acc.z = fmaf(w, b2f(g.z), acc.z); acc.w = fmaf(w, b2f(g.w), acc.w);
            }
        }
    }
    if (do_elu) {
        acc.x = acc.x > 0.f ? acc.x : expm1f(acc.x);
        acc.y = acc.y > 0.f ? acc.y : expm1f(acc.y);
        acc.z = acc.z > 0.f ? acc.z : expm1f(acc.z);
        acc.w = acc.w > 0.f ? acc.w : expm1f(acc.w);
    }
    if constexpr (MODE == 1) {
        ((ushort4*)((unsigned short*)iov + (size_t)p * Hd))[lane] =
            make_ushort4(f2b(acc.x), f2b(acc.y), f2b(acc.z), f2b(acc.w));
    } else if constexpr (MODE == 2) {
        ((float4*)((float*)outv + (size_t)p * Hd))[lane] = acc;
    } else {
        ((float4*)((float*)iov + (size_t)p * Hd))[lane] = acc;
    }
}

extern "C" void kernel_launch(void* const* d_in, const int* in_sizes, int n_in,
                              void* d_out, int out_size, void* d_ws, size_t ws_size,
                              hipStream_t stream) {
    const float* pf    = (const float*)d_in[0];
    const float* ae    = (const float*)d_in[1];
    const int*   wsrc  = (const int*)d_in[2];
    const int*   wdst  = (const int*)d_in[3];
    const float* ww    = (const float*)d_in[4];
    const int*   csrc  = (const int*)d_in[5];
    const int*   cdst  = (const int*)d_in[6];
    const float* cw    = (const float*)d_in[7];
    const float* W1sp  = (const float*)d_in[8];
    const float* b1sp  = (const float*)d_in[9];
    const float* W1sa  = (const float*)d_in[10];
    const float* b1sa  = (const float*)d_in[11];
    const float* W1rw  = (const float*)d_in[12];
    const float* b1rw  = (const float*)d_in[13];
    const float* W1rc  = (const float*)d_in[14];
    const float* b1rc  = (const float*)d_in[15];
    const float* W2sp  = (const float*)d_in[16];
    const float* b2sp  = (const float*)d_in[17];
    const float* W2sa  = (const float*)d_in[18];
    const float* b2sa  = (const float*)d_in[19];
    const float* W2rw  = (const float*)d_in[20];
    const float* b2rw  = (const float*)d_in[21];
    const float* W2rc  = (const float*)d_in[22];
    const float* b2rc  = (const float*)d_in[23];

    const int E_W = in_sizes[2];
    const int E_C = in_sizes[5];

    float* outP = (float*)d_out;                        // [N_P, 256] fp32
    float* outA = outP + (size_t)N_P * Hd;              // [N_A, 256] fp32

    // Workspace layout (R16) + optional pfb + optional selfP:
    float*          xa1    = (float*)d_ws;
    unsigned short* xp1b   = (unsigned short*)(xa1 + (size_t)N_A * Hd);
    unsigned short* msgAll = xp1b + (size_t)N_P * Hd;
    unsigned short* msgP   = msgAll + (size_t)N_A * Hd;
    int*            off    = (int*)(msgAll + (size_t)(N_A + N_P) * Hd);
    int2*           edges  = (int2*)(off + N_P);
    int*            bsum   = (int*)(edges + (E_W + E_C));
    float*          bc1    = (float*)(bsum + 256);
    float*          bcA2   = bc1 + 512;
    float*          bcP2   = bcA2 + 512;
    float*          bcP1   = bcP2 + 512;
    unsigned short* w1h    = (unsigned short*)(bcP1 + 512);
    unsigned short* w1l    = w1h  + (size_t)128 * 512;
    unsigned short* wA2h   = w1l  + (size_t)128 * 512;
    unsigned short* wA2l   = wA2h + (size_t)256 * 512;
    unsigned short* wP2h   = wA2l + (size_t)256 * 512;   // 256*512 shorts
    unsigned short* wP1h   = wP2h + (size_t)256 * 512;   // 512*512 shorts
    unsigned short* pfb    = (unsigned short*)
        (((uintptr_t)(wP1h + (size_t)512 * 512) + 63) & ~(uintptr_t)63);
    unsigned short* selfP  = pfb + (size_t)N_P * F_P;
    const size_t needPfb  = ((char*)(pfb  + (size_t)N_P * F_P)) - (char*)d_ws;
    const size_t needSelf = ((char*)(selfP + (size_t)N_P * Hd)) - (char*)d_ws;
    const bool usePfb  = (ws_size >= needPfb);
    const bool useSelf = (ws_size >= needSelf);

    const dim3 blk(256);
    const int  nb   = (N_P + 1023) / 1024;    // 98
    const int  gM   = (N_P + 127) / 128;      // 782
    const int  gPad = ((gM + 7) / 8) * 8 * 4; // 3136 (XCD-grouped, padded)

    // ---------------- prep ----------------
    prep_kernel<<<1184, 64, 0, stream>>>(W1sa, W1rw, W2sa, W2rw, W2rc, W2sp, W1sp, W1rc,
                                         b1sa, b1rw, b2sa, b2rw, b2rc, b2sp, b1sp, b1rc,
                                         w1h, w1l, wA2h, wA2l, wP2h, wP1h,
                                         bc1, bcA2, bcP2, bcP1);

    // ---------------- combined CSR ----------------
    hipMemsetAsync(off, 0, (size_t)N_P * sizeof(int), stream);
    hist_kernel<<<1024, blk, 0, stream>>>(wdst, E_W, cdst, E_C, off);
    scan1_kernel<<<nb, blk, 0, stream>>>(off, N_P, bsum);
    scan2_kernel<<<1,  blk, 0, stream>>>(bsum, nb);
    scan3_kernel<<<(N_P + 255) / 256, blk, 0, stream>>>(off, N_P, bsum);
    fill_kernel<<<1024, blk, 0, stream>>>(wsrc, wdst, ww, E_W, csrc, cdst, cw, E_C,
                                          off, edges);

    // ---------------- Layer 1 ----------------
    if (usePfb) {
        conv_kernel<<<2048, blk, 0, stream>>>(pf, pfb, (long)N_P * F_P / 4);
        mfma_tile2_kernel<1><<<gPad, blk, 32768, stream>>>(pfb, 512, 16, wP1h, bcP1,
                                                           xp1b, msgP, 1, 1, N_P, gM);
    } else {
        mfma_tile2_kernel<0><<<gPad, blk, 32768, stream>>>(pf, 512, 16, wP1h, bcP1,
                                                           xp1b, msgP, 1, 1, N_P, gM);
    }
    // author self (ELU, fp32 xa1) + writes msg (bf16 into msgAll)
    mfma_dual_kernel<<<N_A / 32, blk, 32 * 128 * 4, stream>>>(ae, 128, w1h, w1l, bc1,
                                                              xa1, msgAll, 1, 0, 0, 1);
    aggregate_kernel<1><<<N_P / 4, blk, 0, stream>>>(xp1b, nullptr, msgAll, off, edges, 1);

    // ---------------- Layer 2 ----------------
    mfma_dual_kernel<<<N_A / 32, blk, 32 * 256 * 4, stream>>>(xa1, 256, wA2h, wA2l, bcA2,
                                                              outA, msgAll, 0, 0, 0, 1);
    if (useSelf) {
        // paper: cites msg (bf16) + self -> bf16 selfP; aggregate reads bf16,
        // writes fp32 d_out (halves GEMM-write + aggregate-read traffic)
        mfma_tile2_kernel<1><<<gPad, blk, 32768, stream>>>(xp1b, 256, 8, wP2h, bcP2,
                                                           msgP, selfP, 1, 1, N_P, gM);
        aggregate_kernel<2><<<N_P / 4, blk, 0, stream>>>(selfP, outP, msgAll, off, edges, 0);
    } else {
        mfma_tile2_kernel<1><<<gPad, blk, 32768, stream>>>(xp1b, 256, 8, wP2h, bcP2,
                                                           msgP, outP, 1, 0, N_P, gM);
        aggregate_kernel<0><<<N_P / 4, blk, 0, stream>>>(outP, nullptr, msgAll, off, edges, 0);
    }
}